// Round 6
// baseline (137.948 us; speedup 1.0000x reference)
//
#include <hip/hip_runtime.h>
#include <hip/hip_bf16.h>

// Problem constants
#define B_  8
#define N_  512
#define C_  1024
#define H_  16
#define HD_ 64
#define M_  4096   // B*N

typedef float  f32x4  __attribute__((ext_vector_type(4)));
typedef __bf16 bf16x8 __attribute__((ext_vector_type(8)));
typedef unsigned short ushort_t;

__device__ __forceinline__ ushort_t f2bf(float f) {
  union { float f; unsigned int u; } un; un.f = f;
  unsigned int u = un.u;
  return (ushort_t)((u + 0x7fffu + ((u >> 16) & 1u)) >> 16);  // RNE
}

// async global->LDS, 16B per lane; lds pointer must be wave-uniform (lane*16 added by HW)
__device__ __forceinline__ void gload16(const void* g, void* l) {
  __builtin_amdgcn_global_load_lds((const __attribute__((address_space(1))) void*)g,
                                   (__attribute__((address_space(3))) void*)l, 16, 0, 0);
}
#define SBAR()  __builtin_amdgcn_s_barrier()
#define SCHED() __builtin_amdgcn_sched_barrier(0)
#define VMCNT4() asm volatile("s_waitcnt vmcnt(4)" ::: "memory")
#define VMCNT0() asm volatile("s_waitcnt vmcnt(0)" ::: "memory")

// ---------------------------------------------------------------------------
// Kernel 1: fused elementwise prep (blocks 0..4095) + weight cast (4096..8191).
//  xb = bf16(x); kp = bf16(mu/bv); vp = bf16(8*mu/bv); bias = log(alpha)-0.5*sum(mu^2/bv)
//  wb = bf16(wq|wk|wv|wp)
// ---------------------------------------------------------------------------
__global__ __launch_bounds__(256) void prep_kernel(
    const float* __restrict__ x, const float* __restrict__ mu,
    const float* __restrict__ logvar, const float* __restrict__ alpha,
    const float* __restrict__ wq, const float* __restrict__ wk,
    const float* __restrict__ wv, const float* __restrict__ wp,
    ushort_t* __restrict__ xb, ushort_t* __restrict__ kp, ushort_t* __restrict__ vp,
    float* __restrict__ biasv, ushort_t* __restrict__ wb) {
  const int t = threadIdx.x;
  if (blockIdx.x >= 4096) {   // weight cast
    int i = ((blockIdx.x - 4096) * 256 + t) * 4;
    int sel = i >> 20;
    int off = i & 0xFFFFF;
    const float* src = sel == 0 ? wq : sel == 1 ? wk : sel == 2 ? wv : wp;
    float4 v = *(const float4*)(src + off);
    ushort4 o;
    o.x = f2bf(v.x); o.y = f2bf(v.y); o.z = f2bf(v.z); o.w = f2bf(v.w);
    *(ushort4*)(wb + i) = o;
    return;
  }
  const int row = blockIdx.x;
  const int base = row * C_ + t * 4;
  float4 xv = *(const float4*)(x + base);
  float4 mv = *(const float4*)(mu + base);
  float4 lv = *(const float4*)(logvar + base);
  float xa[4] = {xv.x, xv.y, xv.z, xv.w};
  float ma[4] = {mv.x, mv.y, mv.z, mv.w};
  float la[4] = {lv.x, lv.y, lv.z, lv.w};
  ushort4 xs, ks, vs;
  ushort_t* xsp = &xs.x; ushort_t* ksp = &ks.x; ushort_t* vsp = &vs.x;
  float l2 = 0.f;
#pragma unroll
  for (int i = 0; i < 4; ++i) {
    float bv  = __expf(la[i]) + 8.0f;   // exp(logvar) + sqrt(HD)
    float inv = 1.0f / bv;
    float kf  = ma[i] * inv;
    float vf  = 8.0f * ma[i] * inv;
    l2 += ma[i] * ma[i] * inv;
    xsp[i] = f2bf(xa[i]); ksp[i] = f2bf(kf); vsp[i] = f2bf(vf);
  }
  *(ushort4*)(xb + base) = xs;
  *(ushort4*)(kp + base) = ks;
  *(ushort4*)(vp + base) = vs;
  l2 += __shfl_xor(l2, 1);  l2 += __shfl_xor(l2, 2);  l2 += __shfl_xor(l2, 4);
  l2 += __shfl_xor(l2, 8);  l2 += __shfl_xor(l2, 16); l2 += __shfl_xor(l2, 32);
  __shared__ float red[4];
  if ((t & 63) == 0) red[t >> 6] = l2;
  __syncthreads();
  if (t == 0) {
    float s = red[0] + red[1] + red[2] + red[3];
    biasv[row] = __logf(alpha[row]) - 0.5f * s;
  }
}

// ---------------------------------------------------------------------------
// GEMM core, 128x128 tile, BK=32, 256 thr (2x2 waves, 64x64/wave), RING-3 LDS
// (3 x 16KB = 48KB -> 3 blocks/CU with __launch_bounds__(256,3)).
// Iter kt: stage tile kt+2 into buf (kt+2)%3 FIRST, compute buf kt%3, then
// publish with vmcnt(4) — drains only the loads issued one full iteration ago
// (never fresh ones). Hazard: buf (kt+2)%3 was read in iter kt-1, whose end
// barrier has passed. Tail: vmcnt(4)@kt=29 covers 30; vmcnt(0)@kt=30 covers 31.
// ---------------------------------------------------------------------------
__device__ __forceinline__ void gemm_tile_r3(const ushort_t* __restrict__ Ag,
                                             const ushort_t* __restrict__ Wg,
                                             int m0, int n0, f32x4 acc[4][4],
                                             ushort_t* lds) {
  const int t = threadIdx.x;
  const int w = t >> 6, lane = t & 63;
  const int wm = w >> 1, wn = w & 1;
  const int chunk = lane >> 4, r15 = lane & 15;
  const int s0 = t, s1 = t + 256;

#define RSTAGE(kt, buf)                                                           \
  do {                                                                            \
    const int k0 = (kt) * 32;                                                     \
    gload16(Ag + (size_t)(m0 + (s0 & 127)) * 1024 + k0 + (s0 >> 7) * 8,           \
            lds + (buf) * 4096 + (s0 & ~63) * 8);                                 \
    gload16(Ag + (size_t)(m0 + (s1 & 127)) * 1024 + k0 + (s1 >> 7) * 8,           \
            lds + (buf) * 4096 + (s1 & ~63) * 8);                                 \
    gload16(Wg + (size_t)(n0 + (s0 & 127)) * 1024 + k0 + (s0 >> 7) * 8,           \
            lds + 12288 + (buf) * 4096 + (s0 & ~63) * 8);                         \
    gload16(Wg + (size_t)(n0 + (s1 & 127)) * 1024 + k0 + (s1 >> 7) * 8,           \
            lds + 12288 + (buf) * 4096 + (s1 & ~63) * 8);                         \
  } while (0)

#define RCOMPUTE(j)                                                               \
  do {                                                                            \
    const ushort_t* Ab = lds + (j) * 4096;                                        \
    const ushort_t* Bb = lds + 12288 + (j) * 4096;                                \
    bf16x8 af[4], bw[4];                                                          \
    _Pragma("unroll")                                                             \
    for (int mi = 0; mi < 4; ++mi)                                                \
      af[mi] = *(const bf16x8*)(Ab + (chunk * 128 + wm * 64 + mi * 16 + r15) * 8);\
    _Pragma("unroll")                                                             \
    for (int ni = 0; ni < 4; ++ni)                                                \
      bw[ni] = *(const bf16x8*)(Bb + (chunk * 128 + wn * 64 + ni * 16 + r15) * 8);\
    __builtin_amdgcn_s_setprio(1);                                                \
    _Pragma("unroll")                                                             \
    for (int mi = 0; mi < 4; ++mi)                                                \
      _Pragma("unroll")                                                           \
      for (int ni = 0; ni < 4; ++ni)                                              \
        acc[mi][ni] = __builtin_amdgcn_mfma_f32_16x16x32_bf16(af[mi], bw[ni],     \
                                                              acc[mi][ni], 0, 0, 0); \
    __builtin_amdgcn_s_setprio(0);                                                \
    SCHED();                                                                      \
  } while (0)

  RSTAGE(0, 0); RSTAGE(1, 1);
  VMCNT4();                 // 8 outstanding -> 4 : tile 0 fully landed
  SBAR(); SCHED();
  for (int kt0 = 0; kt0 < 30; kt0 += 3) {   // kt = 0..29, buf j = kt%3
    RSTAGE(kt0 + 2, 2); RCOMPUTE(0); VMCNT4(); SBAR(); SCHED();
    RSTAGE(kt0 + 3, 0); RCOMPUTE(1); VMCNT4(); SBAR(); SCHED();
    RSTAGE(kt0 + 4, 1); RCOMPUTE(2); VMCNT4(); SBAR(); SCHED();
  }
  // kt=30 (buf 0): tile 31 already staged; drain it for the last iter
  RCOMPUTE(0); VMCNT0(); SBAR(); SCHED();
  // kt=31 (buf 1)
  RCOMPUTE(1);
#undef RSTAGE
#undef RCOMPUTE
}

// ---------------------------------------------------------------------------
// Kernel 2: Q/K/V projections. blockIdx.z selects which. 768 blocks, 3/CU.
//  z=0: Q = xb@wq^T -> Qg ; z=1: K = kp@wk^T -> Kg
//  z=2: V = vp@wv^T -> Vt per-head transposed: Vt[((b*16+h)*64+d)*512 + pos]
// ---------------------------------------------------------------------------
__global__ __launch_bounds__(256, 3) void gemm_qkv_kernel(
    const ushort_t* __restrict__ xb, const ushort_t* __restrict__ kp,
    const ushort_t* __restrict__ vp, const ushort_t* __restrict__ wb,
    ushort_t* __restrict__ Qg, ushort_t* __restrict__ Kg, ushort_t* __restrict__ Vt) {
  __shared__ ushort_t lds[24576];   // 48KB ring-3
  const int z = blockIdx.z;
  const ushort_t* Ag = z == 0 ? xb : z == 1 ? kp : vp;
  const ushort_t* Wg = wb + (size_t)z * 1048576;
  const int m0 = blockIdx.x * 128, n0 = blockIdx.y * 128;
  f32x4 acc[4][4] = {};
  gemm_tile_r3(Ag, Wg, m0, n0, acc, lds);
  const int t = threadIdx.x, w = t >> 6, lane = t & 63;
  const int wm = w >> 1, wn = w & 1;
  const int rbase = m0 + wm * 64 + (lane >> 4) * 4;
  const int cbase = n0 + wn * 64 + (lane & 15);
  if (z < 2) {
    ushort_t* Out = z == 0 ? Qg : Kg;
#pragma unroll
    for (int mi = 0; mi < 4; ++mi)
#pragma unroll
      for (int ni = 0; ni < 4; ++ni)
#pragma unroll
        for (int q = 0; q < 4; ++q)
          Out[(size_t)(rbase + mi * 16 + q) * 1024 + cbase + ni * 16] = f2bf(acc[mi][ni][q]);
  } else {
#pragma unroll
    for (int mi = 0; mi < 4; ++mi) {
      int m = rbase + mi * 16;
      int b = m >> 9, pos = m & 511;        // pos multiple of 4 -> 8B aligned store
#pragma unroll
      for (int ni = 0; ni < 4; ++ni) {
        int n = cbase + ni * 16;
        int h = n >> 6, d = n & 63;
        ushort4 o;
        o.x = f2bf(acc[mi][ni][0]); o.y = f2bf(acc[mi][ni][1]);
        o.z = f2bf(acc[mi][ni][2]); o.w = f2bf(acc[mi][ni][3]);
        *(ushort4*)(Vt + (size_t)((b * 16 + h) * 64 + d) * 512 + pos) = o;
      }
    }
  }
}

// ---------------------------------------------------------------------------
// Kernel 3: attention. Block = (b,h) x 64 q-rows; 4 waves, 16 q-rows/wave.
// Full 512-key score row in registers (acc[32] f32x4/lane); register softmax
// via 16-lane shfl; K and V share one 32KB LDS double-buffer; V tile 0
// prefetched under the softmax VALU phase; attn store deferred to the end.
// ---------------------------------------------------------------------------
__global__ __launch_bounds__(256, 2) void attn_kernel(
    const ushort_t* __restrict__ Qg, const ushort_t* __restrict__ Kg,
    const ushort_t* __restrict__ Vt, const float* __restrict__ biasv,
    float* __restrict__ attn_out, ushort_t* __restrict__ Og) {
  __shared__ ushort_t Qt[4096];     // 8KB : [chunk0..7][qrow0..63] x 16B
  __shared__ ushort_t KV[16384];    // 32KB: double buffer, 8192 ushorts each
  __shared__ ushort_t Pl[8192];     // 16KB: per-wave 2048 ushorts
  __shared__ float biasl[512];
  const int bh = blockIdx.x, qt = blockIdx.y;
  const int b = bh >> 4, h = bh & 15;
  const int t = threadIdx.x, w = t >> 6, lane = t & 63;
  const int hi = lane >> 4, r15 = lane & 15;

  {
    float2 bv2 = *(const float2*)(biasv + b * 512 + t * 2);
    biasl[t * 2] = bv2.x; biasl[t * 2 + 1] = bv2.y;
  }
  { // stage Q tile
    int s0 = t, s1 = t + 256;
    gload16(Qg + (size_t)(b * 512 + qt * 64 + (s0 & 63)) * 1024 + h * 64 + (s0 >> 6) * 8,
            Qt + (s0 & ~63) * 8);
    gload16(Qg + (size_t)(b * 512 + qt * 64 + (s1 & 63)) * 1024 + h * 64 + (s1 >> 6) * 8,
            Qt + (s1 & ~63) * 8);
  }

#define STAGE_K(kt, buf)                                                               \
  do {                                                                                 \
    _Pragma("unroll")                                                                  \
    for (int r = 0; r < 4; ++r) {                                                      \
      int s = r * 256 + t; /* chunk=s>>7 (0..7), krow=s&127 */                         \
      gload16(Kg + (size_t)(b * 512 + (kt) * 128 + (s & 127)) * 1024 + h * 64 + (s >> 7) * 8, \
              KV + (buf) * 8192 + (s & ~63) * 8);                                      \
    }                                                                                  \
  } while (0)
#define STAGE_V(kt, buf)                                                               \
  do {                                                                                 \
    _Pragma("unroll")                                                                  \
    for (int r = 0; r < 4; ++r) {                                                      \
      int s = r * 256 + t; /* chunk=s>>6 (0..15), d=s&63 */                            \
      gload16(Vt + (size_t)(bh * 64 + (s & 63)) * 512 + (kt) * 128 + (s >> 6) * 8,     \
              KV + (buf) * 8192 + (s & ~63) * 8);                                      \
    }                                                                                  \
  } while (0)

  STAGE_K(0, 0);
  f32x4 acc[32] = {};
  bf16x8 aq[2];
  int cur = 0;

  // ---- S = Q K^T (2-phase pipelined; last iter prefetches V0) ----
#pragma unroll
  for (int kt = 0; kt < 4; ++kt) {
    if (kt < 3) STAGE_K(kt + 1, cur ^ 1);
    else        STAGE_V(0, cur ^ 1);        // V0 flies through the softmax phase
    VMCNT4();
    SBAR();
    SCHED();
    if (kt == 0) {
#pragma unroll
      for (int ks = 0; ks < 2; ++ks)
        aq[ks] = *(const bf16x8*)(Qt + ((ks * 4 + hi) * 64 + w * 16 + r15) * 8);
    }
    __builtin_amdgcn_s_setprio(1);
#pragma unroll
    for (int mf = 0; mf < 8; ++mf)
#pragma unroll
      for (int ks = 0; ks < 2; ++ks) {
        bf16x8 bk = *(const bf16x8*)(KV + cur * 8192 + ((ks * 4 + hi) * 128 + mf * 16 + r15) * 8);
        acc[kt * 8 + mf] = __builtin_amdgcn_mfma_f32_16x16x32_bf16(aq[ks], bk, acc[kt * 8 + mf], 0, 0, 0);
      }
    __builtin_amdgcn_s_setprio(0);
    SCHED();
    SBAR();
    SCHED();
    cur ^= 1;
  }

  // ---- bias + softmax (registers; row = w*16+hi*4+q, col = f*16+r15) ----
  float mx[4] = {-1e30f, -1e30f, -1e30f, -1e30f};
#pragma unroll
  for (int f = 0; f < 32; ++f) {
    float bv = biasl[f * 16 + r15];
#pragma unroll
    for (int q = 0; q < 4; ++q) {
      acc[f][q] += bv;
      mx[q] = fmaxf(mx[q], acc[f][q]);
    }
  }
#pragma unroll
  for (int q = 0; q < 4; ++q) {
    mx[q] = fmaxf(mx[q], __shfl_xor(mx[q], 1));
    mx[q] = fmaxf(mx[q], __shfl_xor(mx[q], 2));
    mx[q] = fmaxf(mx[q], __shfl_xor(mx[q], 4));
    mx[q] = fmaxf(mx[q], __shfl_xor(mx[q], 8));
  }
  float sm[4] = {0.f, 0.f, 0.f, 0.f};
#pragma unroll
  for (int f = 0; f < 32; ++f)
#pragma unroll
    for (int q = 0; q < 4; ++q) {
      float p = __expf(acc[f][q] - mx[q]);
      acc[f][q] = p;
      sm[q] += p;
    }
#pragma unroll
  for (int q = 0; q < 4; ++q) {
    sm[q] += __shfl_xor(sm[q], 1);
    sm[q] += __shfl_xor(sm[q], 2);
    sm[q] += __shfl_xor(sm[q], 4);
    sm[q] += __shfl_xor(sm[q], 8);
    sm[q] = 1.0f / sm[q];
  }
#pragma unroll
  for (int f = 0; f < 32; ++f)
#pragma unroll
    for (int q = 0; q < 4; ++q)
      acc[f][q] *= sm[q];                   // normalized P, kept for PV + final store

  // ---- O = P V (2-phase; P slab is per-wave private -> no barrier for it) ----
  f32x4 oacc[4] = {};
#pragma unroll
  for (int kt = 0; kt < 4; ++kt) {
    if (kt < 3) STAGE_V(kt + 1, cur ^ 1);
#pragma unroll
    for (int fl = 0; fl < 8; ++fl) {
      int f = kt * 8 + fl;
      int chunkp = fl * 2 + (r15 >> 3);
#pragma unroll
      for (int q = 0; q < 4; ++q)
        Pl[w * 2048 + (chunkp * 16 + hi * 4 + q) * 8 + (lane & 7)] = f2bf(acc[f][q]);
    }
    if (kt < 3) VMCNT4(); else VMCNT0();
    SBAR();
    SCHED();
    __builtin_amdgcn_s_setprio(1);
#pragma unroll
    for (int ks = 0; ks < 4; ++ks) {
      bf16x8 pa = *(const bf16x8*)(Pl + w * 2048 + ((ks * 4 + hi) * 16 + r15) * 8);
#pragma unroll
      for (int df = 0; df < 4; ++df) {
        bf16x8 vb = *(const bf16x8*)(KV + cur * 8192 + ((ks * 4 + hi) * 64 + df * 16 + r15) * 8);
        oacc[df] = __builtin_amdgcn_mfma_f32_16x16x32_bf16(pa, vb, oacc[df], 0, 0, 0);
      }
    }
    __builtin_amdgcn_s_setprio(0);
    SCHED();
    SBAR();
    SCHED();
    cur ^= 1;
  }

  // ---- deferred stores: attn (fp32, mandatory 134MB) then O (bf16) ----
  float* ao = attn_out + ((size_t)bh * 512 + qt * 64 + w * 16 + hi * 4) * 512 + r15;
#pragma unroll
  for (int f = 0; f < 32; ++f)
#pragma unroll
    for (int q = 0; q < 4; ++q)
      ao[(size_t)q * 512 + f * 16] = acc[f][q];

  size_t obase = (size_t)(b * 512 + qt * 64 + w * 16 + hi * 4) * 1024 + h * 64 + r15;
#pragma unroll
  for (int df = 0; df < 4; ++df)
#pragma unroll
    for (int q = 0; q < 4; ++q)
      Og[obase + (size_t)q * 1024 + df * 16] = f2bf(oacc[df][q]);
#undef STAGE_K
#undef STAGE_V
}

// ---------------------------------------------------------------------------
// Kernel 4: out = O @ wp^T + b_p  (fp32 output)
// ---------------------------------------------------------------------------
__global__ __launch_bounds__(256, 3) void gemm_out_kernel(
    const ushort_t* __restrict__ Og, const ushort_t* __restrict__ wb,
    const float* __restrict__ bp, float* __restrict__ out) {
  __shared__ ushort_t lds[24576];
  const int m0 = blockIdx.x * 128, n0 = blockIdx.y * 128;
  f32x4 acc[4][4] = {};
  gemm_tile_r3(Og, wb + 3 * 1048576, m0, n0, acc, lds);
  const int t = threadIdx.x, w = t >> 6, lane = t & 63;
  const int wm = w >> 1, wn = w & 1;
  const int rbase = m0 + wm * 64 + (lane >> 4) * 4;
  const int cbase = n0 + wn * 64 + (lane & 15);
#pragma unroll
  for (int mi = 0; mi < 4; ++mi)
#pragma unroll
    for (int ni = 0; ni < 4; ++ni) {
      float bias = bp[cbase + ni * 16];
#pragma unroll
      for (int q = 0; q < 4; ++q)
        out[(size_t)(rbase + mi * 16 + q) * 1024 + cbase + ni * 16] = acc[mi][ni][q] + bias;
    }
}

// ---------------------------------------------------------------------------
// Launch. Workspace layout (bytes):
//   0     xb (8MB) -> reused as Og after QKV   24MB  Qg (8MB)   48MB wb (8MB)
//   8MB   kp (8MB)                             32MB  Kg (8MB)   56MB biasv(16KB)
//   16MB  vp (8MB)                             40MB  Vt (8MB)
// ---------------------------------------------------------------------------
extern "C" void kernel_launch(void* const* d_in, const int* in_sizes, int n_in,
                              void* d_out, int out_size, void* d_ws, size_t ws_size,
                              hipStream_t stream) {
  const float* x      = (const float*)d_in[0];
  const float* mu     = (const float*)d_in[1];
  const float* logvar = (const float*)d_in[2];
  const float* alpha  = (const float*)d_in[3];
  // d_in[4]=pi, d_in[5]=z : unused by the reference
  const float* wq = (const float*)d_in[6];
  const float* wk = (const float*)d_in[7];
  const float* wv = (const float*)d_in[8];
  const float* wp = (const float*)d_in[9];
  const float* bp = (const float*)d_in[10];

  float* out      = (float*)d_out;
  float* attn_out = out + (size_t)M_ * C_;   // second tuple element, fp32

  char* ws = (char*)d_ws;
  ushort_t* xb    = (ushort_t*)(ws);
  ushort_t* kp    = (ushort_t*)(ws + (size_t)8  * 1048576);
  ushort_t* vp    = (ushort_t*)(ws + (size_t)16 * 1048576);
  ushort_t* Qg    = (ushort_t*)(ws + (size_t)24 * 1048576);
  ushort_t* Kg    = (ushort_t*)(ws + (size_t)32 * 1048576);
  ushort_t* Vt    = (ushort_t*)(ws + (size_t)40 * 1048576);
  ushort_t* wb    = (ushort_t*)(ws + (size_t)48 * 1048576);
  float*    biasv = (float*)   (ws + (size_t)56 * 1048576);
  ushort_t* Og    = xb;   // xb dead after QKV GEMMs; attn runs strictly after

  prep_kernel<<<8192, 256, 0, stream>>>(x, mu, logvar, alpha, wq, wk, wv, wp,
                                        xb, kp, vp, biasv, wb);
  gemm_qkv_kernel<<<dim3(32, 8, 3), 256, 0, stream>>>(xb, kp, vp, wb, Qg, Kg, Vt);
  attn_kernel<<<dim3(128, 8), 256, 0, stream>>>(Qg, Kg, Vt, biasv, attn_out, Og);
  gemm_out_kernel<<<dim3(32, 8), 256, 0, stream>>>(Og, wb, bp, out);
}

// Round 7
// 135.906 us; speedup vs baseline: 1.0150x; 1.0150x over previous
//
#include <hip/hip_runtime.h>
#include <hip/hip_bf16.h>

// Problem constants
#define B_  8
#define N_  512
#define C_  1024
#define H_  16
#define HD_ 64
#define M_  4096   // B*N

typedef float  f32x4  __attribute__((ext_vector_type(4)));
typedef __bf16 bf16x8 __attribute__((ext_vector_type(8)));
typedef unsigned short ushort_t;

__device__ __forceinline__ ushort_t f2bf(float f) {
  union { float f; unsigned int u; } un; un.f = f;
  unsigned int u = un.u;
  return (ushort_t)((u + 0x7fffu + ((u >> 16) & 1u)) >> 16);  // RNE
}

// async global->LDS, 16B per lane; lds pointer must be wave-uniform (lane*16 added by HW)
__device__ __forceinline__ void gload16(const void* g, void* l) {
  __builtin_amdgcn_global_load_lds((const __attribute__((address_space(1))) void*)g,
                                   (__attribute__((address_space(3))) void*)l, 16, 0, 0);
}
#define SBAR()  __builtin_amdgcn_s_barrier()
#define SCHED() __builtin_amdgcn_sched_barrier(0)
#define VMCNT4() asm volatile("s_waitcnt vmcnt(4)" ::: "memory")
#define VMCNT0() asm volatile("s_waitcnt vmcnt(0)" ::: "memory")

// ---------------------------------------------------------------------------
// Kernel 1: fused elementwise prep (blocks 0..4095) + weight cast (4096..8191).
//  xb = bf16(x); kp = bf16(mu/bv); vp = bf16(8*mu/bv); bias = log(alpha)-0.5*sum(mu^2/bv)
//  wb = bf16(wq|wk|wv|wp)
// ---------------------------------------------------------------------------
__global__ __launch_bounds__(256) void prep_kernel(
    const float* __restrict__ x, const float* __restrict__ mu,
    const float* __restrict__ logvar, const float* __restrict__ alpha,
    const float* __restrict__ wq, const float* __restrict__ wk,
    const float* __restrict__ wv, const float* __restrict__ wp,
    ushort_t* __restrict__ xb, ushort_t* __restrict__ kp, ushort_t* __restrict__ vp,
    float* __restrict__ biasv, ushort_t* __restrict__ wb) {
  const int t = threadIdx.x;
  if (blockIdx.x >= 4096) {   // weight cast
    int i = ((blockIdx.x - 4096) * 256 + t) * 4;
    int sel = i >> 20;
    int off = i & 0xFFFFF;
    const float* src = sel == 0 ? wq : sel == 1 ? wk : sel == 2 ? wv : wp;
    float4 v = *(const float4*)(src + off);
    ushort4 o;
    o.x = f2bf(v.x); o.y = f2bf(v.y); o.z = f2bf(v.z); o.w = f2bf(v.w);
    *(ushort4*)(wb + i) = o;
    return;
  }
  const int row = blockIdx.x;
  const int base = row * C_ + t * 4;
  float4 xv = *(const float4*)(x + base);
  float4 mv = *(const float4*)(mu + base);
  float4 lv = *(const float4*)(logvar + base);
  float xa[4] = {xv.x, xv.y, xv.z, xv.w};
  float ma[4] = {mv.x, mv.y, mv.z, mv.w};
  float la[4] = {lv.x, lv.y, lv.z, lv.w};
  ushort4 xs, ks, vs;
  ushort_t* xsp = &xs.x; ushort_t* ksp = &ks.x; ushort_t* vsp = &vs.x;
  float l2 = 0.f;
#pragma unroll
  for (int i = 0; i < 4; ++i) {
    float bv  = __expf(la[i]) + 8.0f;   // exp(logvar) + sqrt(HD)
    float inv = 1.0f / bv;
    float kf  = ma[i] * inv;
    float vf  = 8.0f * ma[i] * inv;
    l2 += ma[i] * ma[i] * inv;
    xsp[i] = f2bf(xa[i]); ksp[i] = f2bf(kf); vsp[i] = f2bf(vf);
  }
  *(ushort4*)(xb + base) = xs;
  *(ushort4*)(kp + base) = ks;
  *(ushort4*)(vp + base) = vs;
  l2 += __shfl_xor(l2, 1);  l2 += __shfl_xor(l2, 2);  l2 += __shfl_xor(l2, 4);
  l2 += __shfl_xor(l2, 8);  l2 += __shfl_xor(l2, 16); l2 += __shfl_xor(l2, 32);
  __shared__ float red[4];
  if ((t & 63) == 0) red[t >> 6] = l2;
  __syncthreads();
  if (t == 0) {
    float s = red[0] + red[1] + red[2] + red[3];
    biasv[row] = __logf(alpha[row]) - 0.5f * s;
  }
}

// ---------------------------------------------------------------------------
// GEMM core, 128x128 tile, BK=32, 256 thr (2x2 waves, 64x64/wave), RING-3 LDS
// (3 x 16KB = 48KB -> 3 blocks/CU with __launch_bounds__(256,3)).
// Iter kt: stage tile kt+2 into buf (kt+2)%3 FIRST, compute buf kt%3, then
// publish with vmcnt(4) — drains only the loads issued one full iteration ago.
// ---------------------------------------------------------------------------
__device__ __forceinline__ void gemm_tile_r3(const ushort_t* __restrict__ Ag,
                                             const ushort_t* __restrict__ Wg,
                                             int m0, int n0, f32x4 acc[4][4],
                                             ushort_t* lds) {
  const int t = threadIdx.x;
  const int w = t >> 6, lane = t & 63;
  const int wm = w >> 1, wn = w & 1;
  const int chunk = lane >> 4, r15 = lane & 15;
  const int s0 = t, s1 = t + 256;

#define RSTAGE(kt, buf)                                                           \
  do {                                                                            \
    const int k0 = (kt) * 32;                                                     \
    gload16(Ag + (size_t)(m0 + (s0 & 127)) * 1024 + k0 + (s0 >> 7) * 8,           \
            lds + (buf) * 4096 + (s0 & ~63) * 8);                                 \
    gload16(Ag + (size_t)(m0 + (s1 & 127)) * 1024 + k0 + (s1 >> 7) * 8,           \
            lds + (buf) * 4096 + (s1 & ~63) * 8);                                 \
    gload16(Wg + (size_t)(n0 + (s0 & 127)) * 1024 + k0 + (s0 >> 7) * 8,           \
            lds + 12288 + (buf) * 4096 + (s0 & ~63) * 8);                         \
    gload16(Wg + (size_t)(n0 + (s1 & 127)) * 1024 + k0 + (s1 >> 7) * 8,           \
            lds + 12288 + (buf) * 4096 + (s1 & ~63) * 8);                         \
  } while (0)

#define RCOMPUTE(j)                                                               \
  do {                                                                            \
    const ushort_t* Ab = lds + (j) * 4096;                                        \
    const ushort_t* Bb = lds + 12288 + (j) * 4096;                                \
    bf16x8 af[4], bw[4];                                                          \
    _Pragma("unroll")                                                             \
    for (int mi = 0; mi < 4; ++mi)                                                \
      af[mi] = *(const bf16x8*)(Ab + (chunk * 128 + wm * 64 + mi * 16 + r15) * 8);\
    _Pragma("unroll")                                                             \
    for (int ni = 0; ni < 4; ++ni)                                                \
      bw[ni] = *(const bf16x8*)(Bb + (chunk * 128 + wn * 64 + ni * 16 + r15) * 8);\
    __builtin_amdgcn_s_setprio(1);                                                \
    _Pragma("unroll")                                                             \
    for (int mi = 0; mi < 4; ++mi)                                                \
      _Pragma("unroll")                                                           \
      for (int ni = 0; ni < 4; ++ni)                                              \
        acc[mi][ni] = __builtin_amdgcn_mfma_f32_16x16x32_bf16(af[mi], bw[ni],     \
                                                              acc[mi][ni], 0, 0, 0); \
    __builtin_amdgcn_s_setprio(0);                                                \
    SCHED();                                                                      \
  } while (0)

  RSTAGE(0, 0); RSTAGE(1, 1);
  VMCNT4();                 // 8 outstanding -> 4 : tile 0 fully landed
  SBAR(); SCHED();
  for (int kt0 = 0; kt0 < 30; kt0 += 3) {   // kt = 0..29, buf j = kt%3
    RSTAGE(kt0 + 2, 2); RCOMPUTE(0); VMCNT4(); SBAR(); SCHED();
    RSTAGE(kt0 + 3, 0); RCOMPUTE(1); VMCNT4(); SBAR(); SCHED();
    RSTAGE(kt0 + 4, 1); RCOMPUTE(2); VMCNT4(); SBAR(); SCHED();
  }
  // kt=30 (buf 0): tile 31 already staged; drain it for the last iter
  RCOMPUTE(0); VMCNT0(); SBAR(); SCHED();
  // kt=31 (buf 1)
  RCOMPUTE(1);
#undef RSTAGE
#undef RCOMPUTE
}

// ---------------------------------------------------------------------------
// Kernel 2: Q/K/V projections. blockIdx.z selects which. 768 blocks, 3/CU.
// NEW: vectorized epilogue via LDS transpose (ring LDS dead after K-loop):
//  z<2 : acc -> T[row][col] (pad 136) -> bf16x8 row stores, 256B/16-lane runs.
//  z=2 : acc -> T[row][col] (pad 129) -> column gather -> bf16x8 stores
//        contiguous in pos (replaces 64-lane x 8B x 1KB-stride scatter).
// ---------------------------------------------------------------------------
__global__ __launch_bounds__(256, 3) void gemm_qkv_kernel(
    const ushort_t* __restrict__ xb, const ushort_t* __restrict__ kp,
    const ushort_t* __restrict__ vp, const ushort_t* __restrict__ wb,
    ushort_t* __restrict__ Qg, ushort_t* __restrict__ Kg, ushort_t* __restrict__ Vt) {
  __shared__ ushort_t lds[24576];   // 48KB ring-3; reused as transpose buffer
  const int z = blockIdx.z;
  const ushort_t* Ag = z == 0 ? xb : z == 1 ? kp : vp;
  const ushort_t* Wg = wb + (size_t)z * 1048576;
  const int m0 = blockIdx.x * 128, n0 = blockIdx.y * 128;
  f32x4 acc[4][4] = {};
  gemm_tile_r3(Ag, Wg, m0, n0, acc, lds);
  const int t = threadIdx.x, w = t >> 6, lane = t & 63;
  const int wm = w >> 1, wn = w & 1;
  const int hi = lane >> 4, r15 = lane & 15;

  __syncthreads();   // all waves done reading ring bufs before we overwrite as T
  if (z < 2) {
    ushort_t* T = lds;                       // [128][136] bf16, 34.8KB
#pragma unroll
    for (int mi = 0; mi < 4; ++mi)
#pragma unroll
      for (int ni = 0; ni < 4; ++ni)
#pragma unroll
        for (int q = 0; q < 4; ++q) {
          int row = wm * 64 + mi * 16 + hi * 4 + q;
          int col = wn * 64 + ni * 16 + r15;
          T[row * 136 + col] = f2bf(acc[mi][ni][q]);
        }
    __syncthreads();
    ushort_t* Out = z == 0 ? Qg : Kg;
#pragma unroll
    for (int i = 0; i < 8; ++i) {
      int c = t + 256 * i;                   // 2048 chunks of 8 cols
      int row = c >> 4, col0 = (c & 15) * 8;
      bf16x8 v = *(const bf16x8*)(T + row * 136 + col0);   // 16B-aligned (136=8*17)
      *(bf16x8*)(Out + (size_t)(m0 + row) * 1024 + n0 + col0) = v;
    }
  } else {
    ushort_t* T = lds;                       // [128][129] bf16, 33KB (odd pad: col reads 2-way)
#pragma unroll
    for (int mi = 0; mi < 4; ++mi)
#pragma unroll
      for (int ni = 0; ni < 4; ++ni)
#pragma unroll
        for (int q = 0; q < 4; ++q) {
          int row = wm * 64 + mi * 16 + hi * 4 + q;
          int col = wn * 64 + ni * 16 + r15;
          T[row * 129 + col] = f2bf(acc[mi][ni][q]);
        }
    __syncthreads();
    const int b  = m0 >> 9;                  // 128-row tile lies within one batch b
    const int pb = m0 & 511;                 // pos base of tile
#pragma unroll
    for (int i = 0; i < 8; ++i) {
      int c = t + 256 * i;                   // 2048 chunks: 128 d x 16 pos-chunks
      int pc = c & 15, dl = c >> 4;          // lanes -> consecutive pos-chunks
      bf16x8 v;
#pragma unroll
      for (int j = 0; j < 8; ++j)
        v[j] = *(const __bf16*)(T + (pc * 8 + j) * 129 + dl);
      int n = n0 + dl;
      int h = n >> 6, d = n & 63;
      *(bf16x8*)(Vt + (size_t)((b * 16 + h) * 64 + d) * 512 + pb + pc * 8) = v;
    }
  }
}

// ---------------------------------------------------------------------------
// Kernel 3: attention. Block = (b,h) x 64 q-rows; 4 waves, 16 q-rows/wave.
// Full 512-key score row in registers (acc[32] f32x4/lane); register softmax
// via 16-lane shfl; K and V share one 32KB LDS double-buffer; V tile 0
// prefetched under the softmax VALU phase; attn store deferred to the end.
// ---------------------------------------------------------------------------
__global__ __launch_bounds__(256, 2) void attn_kernel(
    const ushort_t* __restrict__ Qg, const ushort_t* __restrict__ Kg,
    const ushort_t* __restrict__ Vt, const float* __restrict__ biasv,
    float* __restrict__ attn_out, ushort_t* __restrict__ Og) {
  __shared__ ushort_t Qt[4096];     // 8KB : [chunk0..7][qrow0..63] x 16B
  __shared__ ushort_t KV[16384];    // 32KB: double buffer, 8192 ushorts each
  __shared__ ushort_t Pl[8192];     // 16KB: per-wave 2048 ushorts
  __shared__ float biasl[512];
  const int bh = blockIdx.x, qt = blockIdx.y;
  const int b = bh >> 4, h = bh & 15;
  const int t = threadIdx.x, w = t >> 6, lane = t & 63;
  const int hi = lane >> 4, r15 = lane & 15;

  {
    float2 bv2 = *(const float2*)(biasv + b * 512 + t * 2);
    biasl[t * 2] = bv2.x; biasl[t * 2 + 1] = bv2.y;
  }
  { // stage Q tile
    int s0 = t, s1 = t + 256;
    gload16(Qg + (size_t)(b * 512 + qt * 64 + (s0 & 63)) * 1024 + h * 64 + (s0 >> 6) * 8,
            Qt + (s0 & ~63) * 8);
    gload16(Qg + (size_t)(b * 512 + qt * 64 + (s1 & 63)) * 1024 + h * 64 + (s1 >> 6) * 8,
            Qt + (s1 & ~63) * 8);
  }

#define STAGE_K(kt, buf)                                                               \
  do {                                                                                 \
    _Pragma("unroll")                                                                  \
    for (int r = 0; r < 4; ++r) {                                                      \
      int s = r * 256 + t; /* chunk=s>>7 (0..7), krow=s&127 */                         \
      gload16(Kg + (size_t)(b * 512 + (kt) * 128 + (s & 127)) * 1024 + h * 64 + (s >> 7) * 8, \
              KV + (buf) * 8192 + (s & ~63) * 8);                                      \
    }                                                                                  \
  } while (0)
#define STAGE_V(kt, buf)                                                               \
  do {                                                                                 \
    _Pragma("unroll")                                                                  \
    for (int r = 0; r < 4; ++r) {                                                      \
      int s = r * 256 + t; /* chunk=s>>6 (0..15), d=s&63 */                            \
      gload16(Vt + (size_t)(bh * 64 + (s & 63)) * 512 + (kt) * 128 + (s >> 6) * 8,     \
              KV + (buf) * 8192 + (s & ~63) * 8);                                      \
    }                                                                                  \
  } while (0)

  STAGE_K(0, 0);
  f32x4 acc[32] = {};
  bf16x8 aq[2];
  int cur = 0;

  // ---- S = Q K^T (2-phase pipelined; last iter prefetches V0) ----
#pragma unroll
  for (int kt = 0; kt < 4; ++kt) {
    if (kt < 3) STAGE_K(kt + 1, cur ^ 1);
    else        STAGE_V(0, cur ^ 1);        // V0 flies through the softmax phase
    VMCNT4();
    SBAR();
    SCHED();
    if (kt == 0) {
#pragma unroll
      for (int ks = 0; ks < 2; ++ks)
        aq[ks] = *(const bf16x8*)(Qt + ((ks * 4 + hi) * 64 + w * 16 + r15) * 8);
    }
    __builtin_amdgcn_s_setprio(1);
#pragma unroll
    for (int mf = 0; mf < 8; ++mf)
#pragma unroll
      for (int ks = 0; ks < 2; ++ks) {
        bf16x8 bk = *(const bf16x8*)(KV + cur * 8192 + ((ks * 4 + hi) * 128 + mf * 16 + r15) * 8);
        acc[kt * 8 + mf] = __builtin_amdgcn_mfma_f32_16x16x32_bf16(aq[ks], bk, acc[kt * 8 + mf], 0, 0, 0);
      }
    __builtin_amdgcn_s_setprio(0);
    SCHED();
    SBAR();
    SCHED();
    cur ^= 1;
  }

  // ---- bias + softmax (registers; row = w*16+hi*4+q, col = f*16+r15) ----
  float mx[4] = {-1e30f, -1e30f, -1e30f, -1e30f};
#pragma unroll
  for (int f = 0; f < 32; ++f) {
    float bv = biasl[f * 16 + r15];
#pragma unroll
    for (int q = 0; q < 4; ++q) {
      acc[f][q] += bv;
      mx[q] = fmaxf(mx[q], acc[f][q]);
    }
  }
#pragma unroll
  for (int q = 0; q < 4; ++q) {
    mx[q] = fmaxf(mx[q], __shfl_xor(mx[q], 1));
    mx[q] = fmaxf(mx[q], __shfl_xor(mx[q], 2));
    mx[q] = fmaxf(mx[q], __shfl_xor(mx[q], 4));
    mx[q] = fmaxf(mx[q], __shfl_xor(mx[q], 8));
  }
  float sm[4] = {0.f, 0.f, 0.f, 0.f};
#pragma unroll
  for (int f = 0; f < 32; ++f)
#pragma unroll
    for (int q = 0; q < 4; ++q) {
      float p = __expf(acc[f][q] - mx[q]);
      acc[f][q] = p;
      sm[q] += p;
    }
#pragma unroll
  for (int q = 0; q < 4; ++q) {
    sm[q] += __shfl_xor(sm[q], 1);
    sm[q] += __shfl_xor(sm[q], 2);
    sm[q] += __shfl_xor(sm[q], 4);
    sm[q] += __shfl_xor(sm[q], 8);
    sm[q] = 1.0f / sm[q];
  }
#pragma unroll
  for (int f = 0; f < 32; ++f)
#pragma unroll
    for (int q = 0; q < 4; ++q)
      acc[f][q] *= sm[q];                   // normalized P, kept for PV + final store

  // ---- O = P V (2-phase; P slab is per-wave private -> no barrier for it) ----
  f32x4 oacc[4] = {};
#pragma unroll
  for (int kt = 0; kt < 4; ++kt) {
    if (kt < 3) STAGE_V(kt + 1, cur ^ 1);
#pragma unroll
    for (int fl = 0; fl < 8; ++fl) {
      int f = kt * 8 + fl;
      int chunkp = fl * 2 + (r15 >> 3);
#pragma unroll
      for (int q = 0; q < 4; ++q)
        Pl[w * 2048 + (chunkp * 16 + hi * 4 + q) * 8 + (lane & 7)] = f2bf(acc[f][q]);
    }
    if (kt < 3) VMCNT4(); else VMCNT0();
    SBAR();
    SCHED();
    __builtin_amdgcn_s_setprio(1);
#pragma unroll
    for (int ks = 0; ks < 4; ++ks) {
      bf16x8 pa = *(const bf16x8*)(Pl + w * 2048 + ((ks * 4 + hi) * 16 + r15) * 8);
#pragma unroll
      for (int df = 0; df < 4; ++df) {
        bf16x8 vb = *(const bf16x8*)(KV + cur * 8192 + ((ks * 4 + hi) * 64 + df * 16 + r15) * 8);
        oacc[df] = __builtin_amdgcn_mfma_f32_16x16x32_bf16(pa, vb, oacc[df], 0, 0, 0);
      }
    }
    __builtin_amdgcn_s_setprio(0);
    SCHED();
    SBAR();
    SCHED();
    cur ^= 1;
  }

  // ---- deferred stores: attn (fp32, mandatory 134MB) then O (bf16) ----
  float* ao = attn_out + ((size_t)bh * 512 + qt * 64 + w * 16 + hi * 4) * 512 + r15;
#pragma unroll
  for (int f = 0; f < 32; ++f)
#pragma unroll
    for (int q = 0; q < 4; ++q)
      ao[(size_t)q * 512 + f * 16] = acc[f][q];

  size_t obase = (size_t)(b * 512 + qt * 64 + w * 16 + hi * 4) * 1024 + h * 64 + r15;
#pragma unroll
  for (int df = 0; df < 4; ++df)
#pragma unroll
    for (int q = 0; q < 4; ++q)
      Og[obase + (size_t)q * 1024 + df * 16] = f2bf(oacc[df][q]);
#undef STAGE_K
#undef STAGE_V
}

// ---------------------------------------------------------------------------
// Kernel 4: out = O @ wp^T + b_p  (fp32 output)
// ---------------------------------------------------------------------------
__global__ __launch_bounds__(256, 3) void gemm_out_kernel(
    const ushort_t* __restrict__ Og, const ushort_t* __restrict__ wb,
    const float* __restrict__ bp, float* __restrict__ out) {
  __shared__ ushort_t lds[24576];
  const int m0 = blockIdx.x * 128, n0 = blockIdx.y * 128;
  f32x4 acc[4][4] = {};
  gemm_tile_r3(Og, wb + 3 * 1048576, m0, n0, acc, lds);
  const int t = threadIdx.x, w = t >> 6, lane = t & 63;
  const int wm = w >> 1, wn = w & 1;
  const int rbase = m0 + wm * 64 + (lane >> 4) * 4;
  const int cbase = n0 + wn * 64 + (lane & 15);
#pragma unroll
  for (int mi = 0; mi < 4; ++mi)
#pragma unroll
    for (int ni = 0; ni < 4; ++ni) {
      float bias = bp[cbase + ni * 16];
#pragma unroll
      for (int q = 0; q < 4; ++q)
        out[(size_t)(rbase + mi * 16 + q) * 1024 + cbase + ni * 16] = acc[mi][ni][q] + bias;
    }
}

// ---------------------------------------------------------------------------
// Launch. Workspace layout (bytes):
//   0     xb (8MB) -> reused as Og after QKV   24MB  Qg (8MB)   48MB wb (8MB)
//   8MB   kp (8MB)                             32MB  Kg (8MB)   56MB biasv(16KB)
//   16MB  vp (8MB)                             40MB  Vt (8MB)
// ---------------------------------------------------------------------------
extern "C" void kernel_launch(void* const* d_in, const int* in_sizes, int n_in,
                              void* d_out, int out_size, void* d_ws, size_t ws_size,
                              hipStream_t stream) {
  const float* x      = (const float*)d_in[0];
  const float* mu     = (const float*)d_in[1];
  const float* logvar = (const float*)d_in[2];
  const float* alpha  = (const float*)d_in[3];
  // d_in[4]=pi, d_in[5]=z : unused by the reference
  const float* wq = (const float*)d_in[6];
  const float* wk = (const float*)d_in[7];
  const float* wv = (const float*)d_in[8];
  const float* wp = (const float*)d_in[9];
  const float* bp = (const float*)d_in[10];

  float* out      = (float*)d_out;
  float* attn_out = out + (size_t)M_ * C_;   // second tuple element, fp32

  char* ws = (char*)d_ws;
  ushort_t* xb    = (ushort_t*)(ws);
  ushort_t* kp    = (ushort_t*)(ws + (size_t)8  * 1048576);
  ushort_t* vp    = (ushort_t*)(ws + (size_t)16 * 1048576);
  ushort_t* Qg    = (ushort_t*)(ws + (size_t)24 * 1048576);
  ushort_t* Kg    = (ushort_t*)(ws + (size_t)32 * 1048576);
  ushort_t* Vt    = (ushort_t*)(ws + (size_t)40 * 1048576);
  ushort_t* wb    = (ushort_t*)(ws + (size_t)48 * 1048576);
  float*    biasv = (float*)   (ws + (size_t)56 * 1048576);
  ushort_t* Og    = xb;   // xb dead after QKV GEMMs; attn runs strictly after

  prep_kernel<<<8192, 256, 0, stream>>>(x, mu, logvar, alpha, wq, wk, wv, wp,
                                        xb, kp, vp, biasv, wb);
  gemm_qkv_kernel<<<dim3(32, 8, 3), 256, 0, stream>>>(xb, kp, vp, wb, Qg, Kg, Vt);
  attn_kernel<<<dim3(128, 8), 256, 0, stream>>>(Qg, Kg, Vt, biasv, attn_out, Og);
  gemm_out_kernel<<<dim3(32, 8), 256, 0, stream>>>(Og, wb, bp, out);
}

// Round 8
// 130.328 us; speedup vs baseline: 1.0585x; 1.0428x over previous
//
#include <hip/hip_runtime.h>
#include <hip/hip_bf16.h>

// Problem constants
#define B_  8
#define N_  512
#define C_  1024
#define H_  16
#define HD_ 64
#define M_  4096   // B*N

typedef float  f32x4  __attribute__((ext_vector_type(4)));
typedef __bf16 bf16x8 __attribute__((ext_vector_type(8)));
typedef unsigned short ushort_t;

__device__ __forceinline__ ushort_t f2bf(float f) {
  union { float f; unsigned int u; } un; un.f = f;
  unsigned int u = un.u;
  return (ushort_t)((u + 0x7fffu + ((u >> 16) & 1u)) >> 16);  // RNE
}

// async global->LDS, 16B per lane; lds pointer must be wave-uniform (lane*16 added by HW)
__device__ __forceinline__ void gload16(const void* g, void* l) {
  __builtin_amdgcn_global_load_lds((const __attribute__((address_space(1))) void*)g,
                                   (__attribute__((address_space(3))) void*)l, 16, 0, 0);
}
#define SBAR()  __builtin_amdgcn_s_barrier()
#define SCHED() __builtin_amdgcn_sched_barrier(0)
#define VMCNT4() asm volatile("s_waitcnt vmcnt(4)" ::: "memory")
#define VMCNT0() asm volatile("s_waitcnt vmcnt(0)" ::: "memory")

// Packed GEMM-operand layout (for 4096x1024 A-matrices and 1024x1024 W):
//   PACK(row,k) = (((row>>7)*32 + (k>>5))*4 + ((k>>3)&3))*1024 + (row&127)*8 + (k&7)
// i.e. [mtile][kt][chunk4][row128][8] — exactly the order gemm staging consumes,
// so every global_load_lds is a fully-contiguous 8KB run.

// ---------------------------------------------------------------------------
// Kernel 1: fused prep (blocks 0..4095) + weight cast (4096..8191), both
// writing PACKED layouts.
//  xb=bf16(x); kp=bf16(mu/bv); vp=bf16(8*mu/bv); bias=log(alpha)-0.5*sum(mu^2/bv)
// ---------------------------------------------------------------------------
__global__ __launch_bounds__(256) void prep_kernel(
    const float* __restrict__ x, const float* __restrict__ mu,
    const float* __restrict__ logvar, const float* __restrict__ alpha,
    const float* __restrict__ wq, const float* __restrict__ wk,
    const float* __restrict__ wv, const float* __restrict__ wp,
    ushort_t* __restrict__ xb, ushort_t* __restrict__ kp, ushort_t* __restrict__ vp,
    float* __restrict__ biasv, ushort_t* __restrict__ wb) {
  const int t = threadIdx.x;
  if (blockIdx.x >= 4096) {   // weight cast -> packed
    int i = ((blockIdx.x - 4096) * 256 + t) * 4;
    int sel = i >> 20;
    int off = i & 0xFFFFF;
    const float* src = sel == 0 ? wq : sel == 1 ? wk : sel == 2 ? wv : wp;
    float4 v = *(const float4*)(src + off);
    ushort4 o;
    o.x = f2bf(v.x); o.y = f2bf(v.y); o.z = f2bf(v.z); o.w = f2bf(v.w);
    int n = off >> 10, k4 = off & 1023;
    size_t po = ((size_t)((n >> 7) * 32 + (k4 >> 5)) * 4 + ((k4 >> 3) & 3)) * 1024
              + (n & 127) * 8 + (k4 & 7);
    *(ushort4*)(wb + sel * 1048576 + po) = o;
    return;
  }
  const int row = blockIdx.x;
  const int base = row * C_ + t * 4;
  float4 xv = *(const float4*)(x + base);
  float4 mv = *(const float4*)(mu + base);
  float4 lv = *(const float4*)(logvar + base);
  float xa[4] = {xv.x, xv.y, xv.z, xv.w};
  float ma[4] = {mv.x, mv.y, mv.z, mv.w};
  float la[4] = {lv.x, lv.y, lv.z, lv.w};
  ushort4 xs, ks, vs;
  ushort_t* xsp = &xs.x; ushort_t* ksp = &ks.x; ushort_t* vsp = &vs.x;
  float l2 = 0.f;
#pragma unroll
  for (int i = 0; i < 4; ++i) {
    float bv  = __expf(la[i]) + 8.0f;   // exp(logvar) + sqrt(HD)
    float inv = 1.0f / bv;
    float kf  = ma[i] * inv;
    float vf  = 8.0f * ma[i] * inv;
    l2 += ma[i] * ma[i] * inv;
    xsp[i] = f2bf(xa[i]); ksp[i] = f2bf(kf); vsp[i] = f2bf(vf);
  }
  {
    size_t po = ((size_t)((row >> 7) * 32 + (t >> 3)) * 4 + ((t >> 1) & 3)) * 1024
              + (row & 127) * 8 + (t & 1) * 4;
    *(ushort4*)(xb + po) = xs;
    *(ushort4*)(kp + po) = ks;
    *(ushort4*)(vp + po) = vs;
  }
  l2 += __shfl_xor(l2, 1);  l2 += __shfl_xor(l2, 2);  l2 += __shfl_xor(l2, 4);
  l2 += __shfl_xor(l2, 8);  l2 += __shfl_xor(l2, 16); l2 += __shfl_xor(l2, 32);
  __shared__ float red[4];
  if ((t & 63) == 0) red[t >> 6] = l2;
  __syncthreads();
  if (t == 0) {
    float s = red[0] + red[1] + red[2] + red[3];
    biasv[row] = __logf(alpha[row]) - 0.5f * s;
  }
}

// ---------------------------------------------------------------------------
// GEMM core, 128x128 tile, BK=32, 256 thr, RING-3 LDS (48KB, 3 blocks/CU).
// PACKED operands: staging is 2 fully-contiguous 8KB runs per tile (A and W).
// ---------------------------------------------------------------------------
__device__ __forceinline__ void gemm_tile_r3(const ushort_t* __restrict__ Ag,
                                             const ushort_t* __restrict__ Wg,
                                             int amt, int ant, f32x4 acc[4][4],
                                             ushort_t* lds) {
  const int t = threadIdx.x;
  const int w = t >> 6, lane = t & 63;
  const int wm = w >> 1, wn = w & 1;
  const int chunk = lane >> 4, r15 = lane & 15;
  const int s0 = t, s1 = t + 256;

#define RSTAGE(kt, buf)                                                           \
  do {                                                                            \
    const ushort_t* sa = Ag + (size_t)(amt * 32 + (kt)) * 4096;                   \
    const ushort_t* sb = Wg + (size_t)(ant * 32 + (kt)) * 4096;                   \
    gload16(sa + s0 * 8, lds + (buf) * 4096 + (s0 & ~63) * 8);                    \
    gload16(sa + s1 * 8, lds + (buf) * 4096 + (s1 & ~63) * 8);                    \
    gload16(sb + s0 * 8, lds + 12288 + (buf) * 4096 + (s0 & ~63) * 8);            \
    gload16(sb + s1 * 8, lds + 12288 + (buf) * 4096 + (s1 & ~63) * 8);            \
  } while (0)

#define RCOMPUTE(j)                                                               \
  do {                                                                            \
    const ushort_t* Ab = lds + (j) * 4096;                                        \
    const ushort_t* Bb = lds + 12288 + (j) * 4096;                                \
    bf16x8 af[4], bw[4];                                                          \
    _Pragma("unroll")                                                             \
    for (int mi = 0; mi < 4; ++mi)                                                \
      af[mi] = *(const bf16x8*)(Ab + (chunk * 128 + wm * 64 + mi * 16 + r15) * 8);\
    _Pragma("unroll")                                                             \
    for (int ni = 0; ni < 4; ++ni)                                                \
      bw[ni] = *(const bf16x8*)(Bb + (chunk * 128 + wn * 64 + ni * 16 + r15) * 8);\
    __builtin_amdgcn_s_setprio(1);                                                \
    _Pragma("unroll")                                                             \
    for (int mi = 0; mi < 4; ++mi)                                                \
      _Pragma("unroll")                                                           \
      for (int ni = 0; ni < 4; ++ni)                                              \
        acc[mi][ni] = __builtin_amdgcn_mfma_f32_16x16x32_bf16(af[mi], bw[ni],     \
                                                              acc[mi][ni], 0, 0, 0); \
    __builtin_amdgcn_s_setprio(0);                                                \
    SCHED();                                                                      \
  } while (0)

  RSTAGE(0, 0); RSTAGE(1, 1);
  VMCNT4();
  SBAR(); SCHED();
  for (int kt0 = 0; kt0 < 30; kt0 += 3) {
    RSTAGE(kt0 + 2, 2); RCOMPUTE(0); VMCNT4(); SBAR(); SCHED();
    RSTAGE(kt0 + 3, 0); RCOMPUTE(1); VMCNT4(); SBAR(); SCHED();
    RSTAGE(kt0 + 4, 1); RCOMPUTE(2); VMCNT4(); SBAR(); SCHED();
  }
  RCOMPUTE(0); VMCNT0(); SBAR(); SCHED();
  RCOMPUTE(1);
#undef RSTAGE
#undef RCOMPUTE
}

// ---------------------------------------------------------------------------
// Kernel 2: Q/K/V projections, PACKED outputs for attn staging order:
//  Qhs[bh][qt][chunk8][row64][8]  Khs[bh][kt][chunk8][row128][8]
//  Vts[bh][kt][chunk16][d64][8]
// Epilogue goes through LDS transpose buffer (ring dead after K-loop).
// ---------------------------------------------------------------------------
__global__ __launch_bounds__(256, 3) void gemm_qkv_kernel(
    const ushort_t* __restrict__ xb, const ushort_t* __restrict__ kp,
    const ushort_t* __restrict__ vp, const ushort_t* __restrict__ wb,
    ushort_t* __restrict__ Qhs, ushort_t* __restrict__ Khs, ushort_t* __restrict__ Vts) {
  __shared__ ushort_t lds[24576];
  const int z = blockIdx.z;
  const ushort_t* Ag = z == 0 ? xb : z == 1 ? kp : vp;
  const ushort_t* Wg = wb + (size_t)z * 1048576;
  const int m0 = blockIdx.x * 128, n0 = blockIdx.y * 128;
  f32x4 acc[4][4] = {};
  gemm_tile_r3(Ag, Wg, blockIdx.x, blockIdx.y, acc, lds);
  const int t = threadIdx.x, w = t >> 6, lane = t & 63;
  const int wm = w >> 1, wn = w & 1;
  const int hi = lane >> 4, r15 = lane & 15;
  const int b = m0 >> 9, h0 = n0 >> 6;

  __syncthreads();   // ring reads done before reuse as transpose buffer
  if (z < 2) {
    ushort_t* T = lds;                       // [128][136]
#pragma unroll
    for (int mi = 0; mi < 4; ++mi)
#pragma unroll
      for (int ni = 0; ni < 4; ++ni)
#pragma unroll
        for (int q = 0; q < 4; ++q) {
          int row = wm * 64 + mi * 16 + hi * 4 + q;
          int col = wn * 64 + ni * 16 + r15;
          T[row * 136 + col] = f2bf(acc[mi][ni][q]);
        }
    __syncthreads();
    if (z == 0) {
      const int qt0 = (m0 & 511) >> 6;
#pragma unroll
      for (int i = 0; i < 8; ++i) {
        int c = t + 256 * i;
        int row64 = c & 63, qt_l = (c >> 6) & 1, chunk = (c >> 7) & 7, head_l = (c >> 10) & 1;
        bf16x8 v = *(const bf16x8*)(T + (qt_l * 64 + row64) * 136 + head_l * 64 + chunk * 8);
        int bh = b * 16 + h0 + head_l;
        *(bf16x8*)(Qhs + ((size_t)((bh * 8 + qt0 + qt_l) * 8 + chunk) * 64 + row64) * 8) = v;
      }
    } else {
      const int kt = (m0 & 511) >> 7;
#pragma unroll
      for (int i = 0; i < 8; ++i) {
        int c = t + 256 * i;
        int row128 = c & 127, chunk = (c >> 7) & 7, head_l = (c >> 10) & 1;
        bf16x8 v = *(const bf16x8*)(T + row128 * 136 + head_l * 64 + chunk * 8);
        int bh = b * 16 + h0 + head_l;
        *(bf16x8*)(Khs + ((size_t)((bh * 4 + kt) * 8 + chunk) * 128 + row128) * 8) = v;
      }
    }
  } else {
    ushort_t* T = lds;                       // [128][129] (odd pad for column gather)
#pragma unroll
    for (int mi = 0; mi < 4; ++mi)
#pragma unroll
      for (int ni = 0; ni < 4; ++ni)
#pragma unroll
        for (int q = 0; q < 4; ++q) {
          int row = wm * 64 + mi * 16 + hi * 4 + q;
          int col = wn * 64 + ni * 16 + r15;
          T[row * 129 + col] = f2bf(acc[mi][ni][q]);
        }
    __syncthreads();
    const int kt = (m0 & 511) >> 7;
#pragma unroll
    for (int i = 0; i < 8; ++i) {
      int c = t + 256 * i;
      int d64 = c & 63, head_l = (c >> 6) & 1, chunkp = (c >> 7) & 15;
      bf16x8 v;
#pragma unroll
      for (int j = 0; j < 8; ++j)
        v[j] = *(const __bf16*)(T + (chunkp * 8 + j) * 129 + head_l * 64 + d64);
      int bh = b * 16 + h0 + head_l;
      *(bf16x8*)(Vts + ((size_t)((bh * 4 + kt) * 16 + chunkp) * 64 + d64) * 8) = v;
    }
  }
}

// ---------------------------------------------------------------------------
// Kernel 3: attention. Same internals as R7; staging now reads PACKED Qhs/
// Khs/Vts with fully-linear gload16; Og written PACKED for gemm_out.
// ---------------------------------------------------------------------------
__global__ __launch_bounds__(256, 2) void attn_kernel(
    const ushort_t* __restrict__ Qhs, const ushort_t* __restrict__ Khs,
    const ushort_t* __restrict__ Vts, const float* __restrict__ biasv,
    float* __restrict__ attn_out, ushort_t* __restrict__ Og) {
  __shared__ ushort_t Qt[4096];     // 8KB : [chunk8][row64] x 16B
  __shared__ ushort_t KV[16384];    // 32KB double buffer
  __shared__ ushort_t Pl[8192];     // 16KB per-wave P slabs
  __shared__ float biasl[512];
  const int bh = blockIdx.x, qt = blockIdx.y;
  const int b = bh >> 4, h = bh & 15;
  const int t = threadIdx.x, w = t >> 6, lane = t & 63;
  const int hi = lane >> 4, r15 = lane & 15;

  {
    float2 bv2 = *(const float2*)(biasv + b * 512 + t * 2);
    biasl[t * 2] = bv2.x; biasl[t * 2 + 1] = bv2.y;
  }
  { // stage Q tile: 8KB linear
    const ushort_t* sq = Qhs + (size_t)(bh * 8 + qt) * 4096;
    gload16(sq + t * 8, Qt + (t & ~63) * 8);
    gload16(sq + (t + 256) * 8, Qt + ((t + 256) & ~63) * 8);
  }

#define STAGE_K(kt, buf)                                                               \
  do {                                                                                 \
    const ushort_t* sk = Khs + (size_t)(bh * 4 + (kt)) * 8192;                         \
    _Pragma("unroll")                                                                  \
    for (int r = 0; r < 4; ++r) {                                                      \
      int s = r * 256 + t;                                                             \
      gload16(sk + s * 8, KV + (buf) * 8192 + (s & ~63) * 8);                          \
    }                                                                                  \
  } while (0)
#define STAGE_V(kt, buf)                                                               \
  do {                                                                                 \
    const ushort_t* sv = Vts + (size_t)(bh * 4 + (kt)) * 8192;                         \
    _Pragma("unroll")                                                                  \
    for (int r = 0; r < 4; ++r) {                                                      \
      int s = r * 256 + t;                                                             \
      gload16(sv + s * 8, KV + (buf) * 8192 + (s & ~63) * 8);                          \
    }                                                                                  \
  } while (0)

  STAGE_K(0, 0);
  f32x4 acc[32] = {};
  bf16x8 aq[2];
  int cur = 0;

  // ---- S = Q K^T ----
#pragma unroll
  for (int kt = 0; kt < 4; ++kt) {
    if (kt < 3) STAGE_K(kt + 1, cur ^ 1);
    else        STAGE_V(0, cur ^ 1);
    VMCNT4();
    SBAR();
    SCHED();
    if (kt == 0) {
#pragma unroll
      for (int ks = 0; ks < 2; ++ks)
        aq[ks] = *(const bf16x8*)(Qt + ((ks * 4 + hi) * 64 + w * 16 + r15) * 8);
    }
    __builtin_amdgcn_s_setprio(1);
#pragma unroll
    for (int mf = 0; mf < 8; ++mf)
#pragma unroll
      for (int ks = 0; ks < 2; ++ks) {
        bf16x8 bk = *(const bf16x8*)(KV + cur * 8192 + ((ks * 4 + hi) * 128 + mf * 16 + r15) * 8);
        acc[kt * 8 + mf] = __builtin_amdgcn_mfma_f32_16x16x32_bf16(aq[ks], bk, acc[kt * 8 + mf], 0, 0, 0);
      }
    __builtin_amdgcn_s_setprio(0);
    SCHED();
    SBAR();
    SCHED();
    cur ^= 1;
  }

  // ---- bias + softmax (registers) ----
  float mx[4] = {-1e30f, -1e30f, -1e30f, -1e30f};
#pragma unroll
  for (int f = 0; f < 32; ++f) {
    float bv = biasl[f * 16 + r15];
#pragma unroll
    for (int q = 0; q < 4; ++q) {
      acc[f][q] += bv;
      mx[q] = fmaxf(mx[q], acc[f][q]);
    }
  }
#pragma unroll
  for (int q = 0; q < 4; ++q) {
    mx[q] = fmaxf(mx[q], __shfl_xor(mx[q], 1));
    mx[q] = fmaxf(mx[q], __shfl_xor(mx[q], 2));
    mx[q] = fmaxf(mx[q], __shfl_xor(mx[q], 4));
    mx[q] = fmaxf(mx[q], __shfl_xor(mx[q], 8));
  }
  float sm[4] = {0.f, 0.f, 0.f, 0.f};
#pragma unroll
  for (int f = 0; f < 32; ++f)
#pragma unroll
    for (int q = 0; q < 4; ++q) {
      float p = __expf(acc[f][q] - mx[q]);
      acc[f][q] = p;
      sm[q] += p;
    }
#pragma unroll
  for (int q = 0; q < 4; ++q) {
    sm[q] += __shfl_xor(sm[q], 1);
    sm[q] += __shfl_xor(sm[q], 2);
    sm[q] += __shfl_xor(sm[q], 4);
    sm[q] += __shfl_xor(sm[q], 8);
    sm[q] = 1.0f / sm[q];
  }
#pragma unroll
  for (int f = 0; f < 32; ++f)
#pragma unroll
    for (int q = 0; q < 4; ++q)
      acc[f][q] *= sm[q];

  // ---- O = P V ----
  f32x4 oacc[4] = {};
#pragma unroll
  for (int kt = 0; kt < 4; ++kt) {
    if (kt < 3) STAGE_V(kt + 1, cur ^ 1);
#pragma unroll
    for (int fl = 0; fl < 8; ++fl) {
      int f = kt * 8 + fl;
      int chunkp = fl * 2 + (r15 >> 3);
#pragma unroll
      for (int q = 0; q < 4; ++q)
        Pl[w * 2048 + (chunkp * 16 + hi * 4 + q) * 8 + (lane & 7)] = f2bf(acc[f][q]);
    }
    if (kt < 3) VMCNT4(); else VMCNT0();
    SBAR();
    SCHED();
    __builtin_amdgcn_s_setprio(1);
#pragma unroll
    for (int ks = 0; ks < 4; ++ks) {
      bf16x8 pa = *(const bf16x8*)(Pl + w * 2048 + ((ks * 4 + hi) * 16 + r15) * 8);
#pragma unroll
      for (int df = 0; df < 4; ++df) {
        bf16x8 vb = *(const bf16x8*)(KV + cur * 8192 + ((ks * 4 + hi) * 64 + df * 16 + r15) * 8);
        oacc[df] = __builtin_amdgcn_mfma_f32_16x16x32_bf16(pa, vb, oacc[df], 0, 0, 0);
      }
    }
    __builtin_amdgcn_s_setprio(0);
    SCHED();
    SBAR();
    SCHED();
    cur ^= 1;
  }

  // ---- deferred stores: attn (fp32) then Og (bf16, PACKED for gemm_out) ----
  float* ao = attn_out + ((size_t)bh * 512 + qt * 64 + w * 16 + hi * 4) * 512 + r15;
#pragma unroll
  for (int f = 0; f < 32; ++f)
#pragma unroll
    for (int q = 0; q < 4; ++q)
      ao[(size_t)q * 512 + f * 16] = acc[f][q];

  {
    const int mtile = b * 4 + (qt >> 1);
    const int rowl = (qt & 1) * 64 + w * 16 + hi * 4;
#pragma unroll
    for (int df = 0; df < 4; ++df) {
      int kto = h * 2 + (df >> 1);
      int chunko = (df & 1) * 2 + (r15 >> 3);
      size_t ob = ((size_t)((mtile * 32 + kto) * 4 + chunko) * 1024 + (r15 & 7));
#pragma unroll
      for (int q = 0; q < 4; ++q)
        Og[ob + (size_t)(rowl + q) * 8] = f2bf(oacc[df][q]);
    }
  }
#undef STAGE_K
#undef STAGE_V
}

// ---------------------------------------------------------------------------
// Kernel 4: out = O @ wp^T + b_p  (fp32 output); Og and wp are PACKED.
// ---------------------------------------------------------------------------
__global__ __launch_bounds__(256, 3) void gemm_out_kernel(
    const ushort_t* __restrict__ Og, const ushort_t* __restrict__ wb,
    const float* __restrict__ bp, float* __restrict__ out) {
  __shared__ ushort_t lds[24576];
  const int m0 = blockIdx.x * 128, n0 = blockIdx.y * 128;
  f32x4 acc[4][4] = {};
  gemm_tile_r3(Og, wb + 3 * 1048576, blockIdx.x, blockIdx.y, acc, lds);
  const int t = threadIdx.x, w = t >> 6, lane = t & 63;
  const int wm = w >> 1, wn = w & 1;
  const int rbase = m0 + wm * 64 + (lane >> 4) * 4;
  const int cbase = n0 + wn * 64 + (lane & 15);
#pragma unroll
  for (int mi = 0; mi < 4; ++mi)
#pragma unroll
    for (int ni = 0; ni < 4; ++ni) {
      float bias = bp[cbase + ni * 16];
#pragma unroll
      for (int q = 0; q < 4; ++q)
        out[(size_t)(rbase + mi * 16 + q) * 1024 + cbase + ni * 16] = acc[mi][ni][q] + bias;
    }
}

// ---------------------------------------------------------------------------
// Launch. Workspace (unchanged offsets, all GEMM operands packed):
//   0 xb | 8MB kp | 16MB vp | 24MB Qhs | 32MB Khs | 40MB Vts | 48MB wb | 56MB biasv
//   Og reuses xb (dead after QKV).
// ---------------------------------------------------------------------------
extern "C" void kernel_launch(void* const* d_in, const int* in_sizes, int n_in,
                              void* d_out, int out_size, void* d_ws, size_t ws_size,
                              hipStream_t stream) {
  const float* x      = (const float*)d_in[0];
  const float* mu     = (const float*)d_in[1];
  const float* logvar = (const float*)d_in[2];
  const float* alpha  = (const float*)d_in[3];
  const float* wq = (const float*)d_in[6];
  const float* wk = (const float*)d_in[7];
  const float* wv = (const float*)d_in[8];
  const float* wp = (const float*)d_in[9];
  const float* bp = (const float*)d_in[10];

  float* out      = (float*)d_out;
  float* attn_out = out + (size_t)M_ * C_;

  char* ws = (char*)d_ws;
  ushort_t* xb    = (ushort_t*)(ws);
  ushort_t* kp    = (ushort_t*)(ws + (size_t)8  * 1048576);
  ushort_t* vp    = (ushort_t*)(ws + (size_t)16 * 1048576);
  ushort_t* Qhs   = (ushort_t*)(ws + (size_t)24 * 1048576);
  ushort_t* Khs   = (ushort_t*)(ws + (size_t)32 * 1048576);
  ushort_t* Vts   = (ushort_t*)(ws + (size_t)40 * 1048576);
  ushort_t* wb    = (ushort_t*)(ws + (size_t)48 * 1048576);
  float*    biasv = (float*)   (ws + (size_t)56 * 1048576);
  ushort_t* Og    = xb;

  prep_kernel<<<8192, 256, 0, stream>>>(x, mu, logvar, alpha, wq, wk, wv, wp,
                                        xb, kp, vp, biasv, wb);
  gemm_qkv_kernel<<<dim3(32, 8, 3), 256, 0, stream>>>(xb, kp, vp, wb, Qhs, Khs, Vts);
  attn_kernel<<<dim3(128, 8), 256, 0, stream>>>(Qhs, Khs, Vts, biasv, attn_out, Og);
  gemm_out_kernel<<<dim3(32, 8), 256, 0, stream>>>(Og, wb, bp, out);
}

// Round 9
// 111.218 us; speedup vs baseline: 1.2403x; 1.1718x over previous
//
#include <hip/hip_runtime.h>
#include <hip/hip_bf16.h>

// Problem constants
#define B_  8
#define N_  512
#define C_  1024
#define H_  16
#define HD_ 64
#define M_  4096   // B*N

typedef float  f32x4  __attribute__((ext_vector_type(4)));
typedef __bf16 bf16x8 __attribute__((ext_vector_type(8)));
typedef unsigned short ushort_t;

__device__ __forceinline__ ushort_t f2bf(float f) {
  union { float f; unsigned int u; } un; un.f = f;
  unsigned int u = un.u;
  return (ushort_t)((u + 0x7fffu + ((u >> 16) & 1u)) >> 16);  // RNE
}

// async global->LDS, 16B per lane; lds pointer must be wave-uniform (lane*16 added by HW)
__device__ __forceinline__ void gload16(const void* g, void* l) {
  __builtin_amdgcn_global_load_lds((const __attribute__((address_space(1))) void*)g,
                                   (__attribute__((address_space(3))) void*)l, 16, 0, 0);
}
#define SBAR()  __builtin_amdgcn_s_barrier()
#define SCHED() __builtin_amdgcn_sched_barrier(0)
#define VMCNT4() asm volatile("s_waitcnt vmcnt(4)" ::: "memory")
#define VMCNT0() asm volatile("s_waitcnt vmcnt(0)" ::: "memory")

// Packed GEMM-operand layout (verified R8):
//   PACK(row,k) = (((row>>7)*32 + (k>>5))*4 + ((k>>3)&3))*1024 + (row&127)*8 + (k&7)
// [mtile][kt][chunk4][row128][8] — the exact linear order gemm staging consumes.

// ---------------------------------------------------------------------------
// Kernel 1: tile-packed prep. Block = one [128r x 32k] tile.
//  bid < 1024          : A-tiles (mt,kt): xb=bf16(x), kp=bf16(mu/bv),
//                        vp=bf16(8*mu/bv); l2part[row][kt] = sum_k mu^2/bv
//  bid in [1024, 2048) : W-tiles (sel,nt,kt) -> wb packed
// All packed writes are 2 x 512B dense segments per store instruction.
// ---------------------------------------------------------------------------
__global__ __launch_bounds__(256) void prep_pack_kernel(
    const float* __restrict__ x, const float* __restrict__ mu,
    const float* __restrict__ logvar,
    const float* __restrict__ wq, const float* __restrict__ wk,
    const float* __restrict__ wv, const float* __restrict__ wp,
    ushort_t* __restrict__ xb, ushort_t* __restrict__ kp, ushort_t* __restrict__ vp,
    ushort_t* __restrict__ wb, float* __restrict__ l2part) {
  const int bid = blockIdx.x, t = threadIdx.x;
  const int row = t >> 1, cg = (t & 1) * 16;   // row 0..127, k-group 0 or 16
  const int c0 = cg >> 3;                      // chunk base: 0 or 2

  if (bid < 1024) {
    const int mt = bid >> 5, kt = bid & 31;
    const size_t src = (size_t)(mt * 128 + row) * 1024 + kt * 32 + cg;
    ushort_t tx[16] __attribute__((aligned(16)));
    ushort_t tk[16] __attribute__((aligned(16)));
    ushort_t tv[16] __attribute__((aligned(16)));
    float l2 = 0.f;
#pragma unroll
    for (int j = 0; j < 4; ++j) {
      float4 xv = *(const float4*)(x + src + j * 4);
      float4 mv = *(const float4*)(mu + src + j * 4);
      float4 lv = *(const float4*)(logvar + src + j * 4);
      float xa[4] = {xv.x, xv.y, xv.z, xv.w};
      float ma[4] = {mv.x, mv.y, mv.z, mv.w};
      float la[4] = {lv.x, lv.y, lv.z, lv.w};
#pragma unroll
      for (int i = 0; i < 4; ++i) {
        int e = j * 4 + i;
        float bv  = __expf(la[i]) + 8.0f;   // exp(logvar) + sqrt(HD)
        float inv = 1.0f / bv;
        float kf  = ma[i] * inv;
        l2 += ma[i] * kf;                   // mu^2 / bv
        tx[e] = f2bf(xa[i]); tk[e] = f2bf(kf); tv[e] = f2bf(8.0f * kf);
      }
    }
    const size_t tb = (size_t)((mt * 32 + kt) * 4) * 1024 + row * 8;
    *(bf16x8*)(xb + tb + c0 * 1024)       = *(const bf16x8*)(tx);
    *(bf16x8*)(xb + tb + (c0 + 1) * 1024) = *(const bf16x8*)(tx + 8);
    *(bf16x8*)(kp + tb + c0 * 1024)       = *(const bf16x8*)(tk);
    *(bf16x8*)(kp + tb + (c0 + 1) * 1024) = *(const bf16x8*)(tk + 8);
    *(bf16x8*)(vp + tb + c0 * 1024)       = *(const bf16x8*)(tv);
    *(bf16x8*)(vp + tb + (c0 + 1) * 1024) = *(const bf16x8*)(tv + 8);
    l2 += __shfl_xor(l2, 1);               // pair holds full 32-k partial
    if ((t & 1) == 0) l2part[(size_t)(mt * 128 + row) * 32 + kt] = l2;
  } else {
    const int idx = bid - 1024;
    const int sel = idx >> 8, nt = (idx >> 5) & 7, kt = idx & 31;
    const float* src = sel == 0 ? wq : sel == 1 ? wk : sel == 2 ? wv : wp;
    const size_t so = (size_t)(nt * 128 + row) * 1024 + kt * 32 + cg;
    ushort_t tw[16] __attribute__((aligned(16)));
#pragma unroll
    for (int j = 0; j < 4; ++j) {
      float4 v = *(const float4*)(src + so + j * 4);
      tw[j * 4 + 0] = f2bf(v.x); tw[j * 4 + 1] = f2bf(v.y);
      tw[j * 4 + 2] = f2bf(v.z); tw[j * 4 + 3] = f2bf(v.w);
    }
    ushort_t* dst = wb + (size_t)sel * 1048576;
    const size_t tb = (size_t)((nt * 32 + kt) * 4) * 1024 + row * 8;
    *(bf16x8*)(dst + tb + c0 * 1024)       = *(const bf16x8*)(tw);
    *(bf16x8*)(dst + tb + (c0 + 1) * 1024) = *(const bf16x8*)(tw + 8);
  }
}

// ---------------------------------------------------------------------------
// Kernel 1b: bias reduce. biasv[row] = log(alpha[row]) - 0.5 * sum_kt l2part.
// ---------------------------------------------------------------------------
__global__ __launch_bounds__(256) void bias_reduce_kernel(
    const float* __restrict__ alpha, const float* __restrict__ l2part,
    float* __restrict__ biasv) {
  const int row = blockIdx.x * 256 + threadIdx.x;
  const float* p = l2part + (size_t)row * 32;
  float s = 0.f;
#pragma unroll
  for (int j = 0; j < 8; ++j) {
    float4 v = *(const float4*)(p + j * 4);
    s += (v.x + v.y) + (v.z + v.w);
  }
  biasv[row] = __logf(alpha[row]) - 0.5f * s;
}

// ---------------------------------------------------------------------------
// GEMM core, 128x128 tile, BK=32, 256 thr, RING-3 LDS (48KB, 3 blocks/CU).
// PACKED operands: staging is 2 fully-contiguous 8KB runs per tile (A and W).
// ---------------------------------------------------------------------------
__device__ __forceinline__ void gemm_tile_r3(const ushort_t* __restrict__ Ag,
                                             const ushort_t* __restrict__ Wg,
                                             int amt, int ant, f32x4 acc[4][4],
                                             ushort_t* lds) {
  const int t = threadIdx.x;
  const int w = t >> 6, lane = t & 63;
  const int wm = w >> 1, wn = w & 1;
  const int chunk = lane >> 4, r15 = lane & 15;
  const int s0 = t, s1 = t + 256;

#define RSTAGE(kt, buf)                                                           \
  do {                                                                            \
    const ushort_t* sa = Ag + (size_t)(amt * 32 + (kt)) * 4096;                   \
    const ushort_t* sb = Wg + (size_t)(ant * 32 + (kt)) * 4096;                   \
    gload16(sa + s0 * 8, lds + (buf) * 4096 + (s0 & ~63) * 8);                    \
    gload16(sa + s1 * 8, lds + (buf) * 4096 + (s1 & ~63) * 8);                    \
    gload16(sb + s0 * 8, lds + 12288 + (buf) * 4096 + (s0 & ~63) * 8);            \
    gload16(sb + s1 * 8, lds + 12288 + (buf) * 4096 + (s1 & ~63) * 8);            \
  } while (0)

#define RCOMPUTE(j)                                                               \
  do {                                                                            \
    const ushort_t* Ab = lds + (j) * 4096;                                        \
    const ushort_t* Bb = lds + 12288 + (j) * 4096;                                \
    bf16x8 af[4], bw[4];                                                          \
    _Pragma("unroll")                                                             \
    for (int mi = 0; mi < 4; ++mi)                                                \
      af[mi] = *(const bf16x8*)(Ab + (chunk * 128 + wm * 64 + mi * 16 + r15) * 8);\
    _Pragma("unroll")                                                             \
    for (int ni = 0; ni < 4; ++ni)                                                \
      bw[ni] = *(const bf16x8*)(Bb + (chunk * 128 + wn * 64 + ni * 16 + r15) * 8);\
    __builtin_amdgcn_s_setprio(1);                                                \
    _Pragma("unroll")                                                             \
    for (int mi = 0; mi < 4; ++mi)                                                \
      _Pragma("unroll")                                                           \
      for (int ni = 0; ni < 4; ++ni)                                              \
        acc[mi][ni] = __builtin_amdgcn_mfma_f32_16x16x32_bf16(af[mi], bw[ni],     \
                                                              acc[mi][ni], 0, 0, 0); \
    __builtin_amdgcn_s_setprio(0);                                                \
    SCHED();                                                                      \
  } while (0)

  RSTAGE(0, 0); RSTAGE(1, 1);
  VMCNT4();
  SBAR(); SCHED();
  for (int kt0 = 0; kt0 < 30; kt0 += 3) {
    RSTAGE(kt0 + 2, 2); RCOMPUTE(0); VMCNT4(); SBAR(); SCHED();
    RSTAGE(kt0 + 3, 0); RCOMPUTE(1); VMCNT4(); SBAR(); SCHED();
    RSTAGE(kt0 + 4, 1); RCOMPUTE(2); VMCNT4(); SBAR(); SCHED();
  }
  RCOMPUTE(0); VMCNT0(); SBAR(); SCHED();
  RCOMPUTE(1);
#undef RSTAGE
#undef RCOMPUTE
}

// ---------------------------------------------------------------------------
// Kernel 2: Q/K/V projections, PACKED outputs for attn staging order:
//  Qhs[bh][qt][chunk8][row64][8]  Khs[bh][kt][chunk8][row128][8]
//  Vts[bh][kt][chunk16][d64][8]
// ---------------------------------------------------------------------------
__global__ __launch_bounds__(256, 3) void gemm_qkv_kernel(
    const ushort_t* __restrict__ xb, const ushort_t* __restrict__ kp,
    const ushort_t* __restrict__ vp, const ushort_t* __restrict__ wb,
    ushort_t* __restrict__ Qhs, ushort_t* __restrict__ Khs, ushort_t* __restrict__ Vts) {
  __shared__ ushort_t lds[24576];
  const int z = blockIdx.z;
  const ushort_t* Ag = z == 0 ? xb : z == 1 ? kp : vp;
  const ushort_t* Wg = wb + (size_t)z * 1048576;
  const int m0 = blockIdx.x * 128, n0 = blockIdx.y * 128;
  f32x4 acc[4][4] = {};
  gemm_tile_r3(Ag, Wg, blockIdx.x, blockIdx.y, acc, lds);
  const int t = threadIdx.x, w = t >> 6, lane = t & 63;
  const int wm = w >> 1, wn = w & 1;
  const int hi = lane >> 4, r15 = lane & 15;
  const int b = m0 >> 9, h0 = n0 >> 6;

  __syncthreads();
  if (z < 2) {
    ushort_t* T = lds;                       // [128][136]
#pragma unroll
    for (int mi = 0; mi < 4; ++mi)
#pragma unroll
      for (int ni = 0; ni < 4; ++ni)
#pragma unroll
        for (int q = 0; q < 4; ++q) {
          int row = wm * 64 + mi * 16 + hi * 4 + q;
          int col = wn * 64 + ni * 16 + r15;
          T[row * 136 + col] = f2bf(acc[mi][ni][q]);
        }
    __syncthreads();
    if (z == 0) {
      const int qt0 = (m0 & 511) >> 6;
#pragma unroll
      for (int i = 0; i < 8; ++i) {
        int c = t + 256 * i;
        int row64 = c & 63, qt_l = (c >> 6) & 1, chunk = (c >> 7) & 7, head_l = (c >> 10) & 1;
        bf16x8 v = *(const bf16x8*)(T + (qt_l * 64 + row64) * 136 + head_l * 64 + chunk * 8);
        int bh = b * 16 + h0 + head_l;
        *(bf16x8*)(Qhs + ((size_t)((bh * 8 + qt0 + qt_l) * 8 + chunk) * 64 + row64) * 8) = v;
      }
    } else {
      const int kt = (m0 & 511) >> 7;
#pragma unroll
      for (int i = 0; i < 8; ++i) {
        int c = t + 256 * i;
        int row128 = c & 127, chunk = (c >> 7) & 7, head_l = (c >> 10) & 1;
        bf16x8 v = *(const bf16x8*)(T + row128 * 136 + head_l * 64 + chunk * 8);
        int bh = b * 16 + h0 + head_l;
        *(bf16x8*)(Khs + ((size_t)((bh * 4 + kt) * 8 + chunk) * 128 + row128) * 8) = v;
      }
    }
  } else {
    ushort_t* T = lds;                       // [128][129]
#pragma unroll
    for (int mi = 0; mi < 4; ++mi)
#pragma unroll
      for (int ni = 0; ni < 4; ++ni)
#pragma unroll
        for (int q = 0; q < 4; ++q) {
          int row = wm * 64 + mi * 16 + hi * 4 + q;
          int col = wn * 64 + ni * 16 + r15;
          T[row * 129 + col] = f2bf(acc[mi][ni][q]);
        }
    __syncthreads();
    const int kt = (m0 & 511) >> 7;
#pragma unroll
    for (int i = 0; i < 8; ++i) {
      int c = t + 256 * i;
      int d64 = c & 63, head_l = (c >> 6) & 1, chunkp = (c >> 7) & 15;
      bf16x8 v;
#pragma unroll
      for (int j = 0; j < 8; ++j)
        v[j] = *(const __bf16*)(T + (chunkp * 8 + j) * 129 + head_l * 64 + d64);
      int bh = b * 16 + h0 + head_l;
      *(bf16x8*)(Vts + ((size_t)((bh * 4 + kt) * 16 + chunkp) * 64 + d64) * 8) = v;
    }
  }
}

// ---------------------------------------------------------------------------
// Kernel 3: attention (identical to R8).
// ---------------------------------------------------------------------------
__global__ __launch_bounds__(256, 2) void attn_kernel(
    const ushort_t* __restrict__ Qhs, const ushort_t* __restrict__ Khs,
    const ushort_t* __restrict__ Vts, const float* __restrict__ biasv,
    float* __restrict__ attn_out, ushort_t* __restrict__ Og) {
  __shared__ ushort_t Qt[4096];
  __shared__ ushort_t KV[16384];
  __shared__ ushort_t Pl[8192];
  __shared__ float biasl[512];
  const int bh = blockIdx.x, qt = blockIdx.y;
  const int b = bh >> 4, h = bh & 15;
  const int t = threadIdx.x, w = t >> 6, lane = t & 63;
  const int hi = lane >> 4, r15 = lane & 15;

  {
    float2 bv2 = *(const float2*)(biasv + b * 512 + t * 2);
    biasl[t * 2] = bv2.x; biasl[t * 2 + 1] = bv2.y;
  }
  {
    const ushort_t* sq = Qhs + (size_t)(bh * 8 + qt) * 4096;
    gload16(sq + t * 8, Qt + (t & ~63) * 8);
    gload16(sq + (t + 256) * 8, Qt + ((t + 256) & ~63) * 8);
  }

#define STAGE_K(kt, buf)                                                               \
  do {                                                                                 \
    const ushort_t* sk = Khs + (size_t)(bh * 4 + (kt)) * 8192;                         \
    _Pragma("unroll")                                                                  \
    for (int r = 0; r < 4; ++r) {                                                      \
      int s = r * 256 + t;                                                             \
      gload16(sk + s * 8, KV + (buf) * 8192 + (s & ~63) * 8);                          \
    }                                                                                  \
  } while (0)
#define STAGE_V(kt, buf)                                                               \
  do {                                                                                 \
    const ushort_t* sv = Vts + (size_t)(bh * 4 + (kt)) * 8192;                         \
    _Pragma("unroll")                                                                  \
    for (int r = 0; r < 4; ++r) {                                                      \
      int s = r * 256 + t;                                                             \
      gload16(sv + s * 8, KV + (buf) * 8192 + (s & ~63) * 8);                          \
    }                                                                                  \
  } while (0)

  STAGE_K(0, 0);
  f32x4 acc[32] = {};
  bf16x8 aq[2];
  int cur = 0;

#pragma unroll
  for (int kt = 0; kt < 4; ++kt) {
    if (kt < 3) STAGE_K(kt + 1, cur ^ 1);
    else        STAGE_V(0, cur ^ 1);
    VMCNT4();
    SBAR();
    SCHED();
    if (kt == 0) {
#pragma unroll
      for (int ks = 0; ks < 2; ++ks)
        aq[ks] = *(const bf16x8*)(Qt + ((ks * 4 + hi) * 64 + w * 16 + r15) * 8);
    }
    __builtin_amdgcn_s_setprio(1);
#pragma unroll
    for (int mf = 0; mf < 8; ++mf)
#pragma unroll
      for (int ks = 0; ks < 2; ++ks) {
        bf16x8 bk = *(const bf16x8*)(KV + cur * 8192 + ((ks * 4 + hi) * 128 + mf * 16 + r15) * 8);
        acc[kt * 8 + mf] = __builtin_amdgcn_mfma_f32_16x16x32_bf16(aq[ks], bk, acc[kt * 8 + mf], 0, 0, 0);
      }
    __builtin_amdgcn_s_setprio(0);
    SCHED();
    SBAR();
    SCHED();
    cur ^= 1;
  }

  float mx[4] = {-1e30f, -1e30f, -1e30f, -1e30f};
#pragma unroll
  for (int f = 0; f < 32; ++f) {
    float bv = biasl[f * 16 + r15];
#pragma unroll
    for (int q = 0; q < 4; ++q) {
      acc[f][q] += bv;
      mx[q] = fmaxf(mx[q], acc[f][q]);
    }
  }
#pragma unroll
  for (int q = 0; q < 4; ++q) {
    mx[q] = fmaxf(mx[q], __shfl_xor(mx[q], 1));
    mx[q] = fmaxf(mx[q], __shfl_xor(mx[q], 2));
    mx[q] = fmaxf(mx[q], __shfl_xor(mx[q], 4));
    mx[q] = fmaxf(mx[q], __shfl_xor(mx[q], 8));
  }
  float sm[4] = {0.f, 0.f, 0.f, 0.f};
#pragma unroll
  for (int f = 0; f < 32; ++f)
#pragma unroll
    for (int q = 0; q < 4; ++q) {
      float p = __expf(acc[f][q] - mx[q]);
      acc[f][q] = p;
      sm[q] += p;
    }
#pragma unroll
  for (int q = 0; q < 4; ++q) {
    sm[q] += __shfl_xor(sm[q], 1);
    sm[q] += __shfl_xor(sm[q], 2);
    sm[q] += __shfl_xor(sm[q], 4);
    sm[q] += __shfl_xor(sm[q], 8);
    sm[q] = 1.0f / sm[q];
  }
#pragma unroll
  for (int f = 0; f < 32; ++f)
#pragma unroll
    for (int q = 0; q < 4; ++q)
      acc[f][q] *= sm[q];

  f32x4 oacc[4] = {};
#pragma unroll
  for (int kt = 0; kt < 4; ++kt) {
    if (kt < 3) STAGE_V(kt + 1, cur ^ 1);
#pragma unroll
    for (int fl = 0; fl < 8; ++fl) {
      int f = kt * 8 + fl;
      int chunkp = fl * 2 + (r15 >> 3);
#pragma unroll
      for (int q = 0; q < 4; ++q)
        Pl[w * 2048 + (chunkp * 16 + hi * 4 + q) * 8 + (lane & 7)] = f2bf(acc[f][q]);
    }
    if (kt < 3) VMCNT4(); else VMCNT0();
    SBAR();
    SCHED();
    __builtin_amdgcn_s_setprio(1);
#pragma unroll
    for (int ks = 0; ks < 4; ++ks) {
      bf16x8 pa = *(const bf16x8*)(Pl + w * 2048 + ((ks * 4 + hi) * 16 + r15) * 8);
#pragma unroll
      for (int df = 0; df < 4; ++df) {
        bf16x8 vb = *(const bf16x8*)(KV + cur * 8192 + ((ks * 4 + hi) * 64 + df * 16 + r15) * 8);
        oacc[df] = __builtin_amdgcn_mfma_f32_16x16x32_bf16(pa, vb, oacc[df], 0, 0, 0);
      }
    }
    __builtin_amdgcn_s_setprio(0);
    SCHED();
    SBAR();
    SCHED();
    cur ^= 1;
  }

  float* ao = attn_out + ((size_t)bh * 512 + qt * 64 + w * 16 + hi * 4) * 512 + r15;
#pragma unroll
  for (int f = 0; f < 32; ++f)
#pragma unroll
    for (int q = 0; q < 4; ++q)
      ao[(size_t)q * 512 + f * 16] = acc[f][q];

  {
    const int mtile = b * 4 + (qt >> 1);
    const int rowl = (qt & 1) * 64 + w * 16 + hi * 4;
#pragma unroll
    for (int df = 0; df < 4; ++df) {
      int kto = h * 2 + (df >> 1);
      int chunko = (df & 1) * 2 + (r15 >> 3);
      size_t ob = ((size_t)((mtile * 32 + kto) * 4 + chunko) * 1024 + (r15 & 7));
#pragma unroll
      for (int q = 0; q < 4; ++q)
        Og[ob + (size_t)(rowl + q) * 8] = f2bf(oacc[df][q]);
    }
  }
#undef STAGE_K
#undef STAGE_V
}

// ---------------------------------------------------------------------------
// Kernel 4: out = O @ wp^T + b_p  (fp32 output); Og and wp are PACKED.
// ---------------------------------------------------------------------------
__global__ __launch_bounds__(256, 3) void gemm_out_kernel(
    const ushort_t* __restrict__ Og, const ushort_t* __restrict__ wb,
    const float* __restrict__ bp, float* __restrict__ out) {
  __shared__ ushort_t lds[24576];
  const int m0 = blockIdx.x * 128, n0 = blockIdx.y * 128;
  f32x4 acc[4][4] = {};
  gemm_tile_r3(Og, wb + 3 * 1048576, blockIdx.x, blockIdx.y, acc, lds);
  const int t = threadIdx.x, w = t >> 6, lane = t & 63;
  const int wm = w >> 1, wn = w & 1;
  const int rbase = m0 + wm * 64 + (lane >> 4) * 4;
  const int cbase = n0 + wn * 64 + (lane & 15);
#pragma unroll
  for (int mi = 0; mi < 4; ++mi)
#pragma unroll
    for (int ni = 0; ni < 4; ++ni) {
      float bias = bp[cbase + ni * 16];
#pragma unroll
      for (int q = 0; q < 4; ++q)
        out[(size_t)(rbase + mi * 16 + q) * 1024 + cbase + ni * 16] = acc[mi][ni][q] + bias;
    }
}

// ---------------------------------------------------------------------------
// Launch. Workspace:
//   0 xb | 8MB kp | 16MB vp | 24MB Qhs | 32MB Khs | 40MB Vts | 48MB wb
//   56MB biasv (16KB) | 57MB l2part (512KB).  Og reuses xb.
// ---------------------------------------------------------------------------
extern "C" void kernel_launch(void* const* d_in, const int* in_sizes, int n_in,
                              void* d_out, int out_size, void* d_ws, size_t ws_size,
                              hipStream_t stream) {
  const float* x      = (const float*)d_in[0];
  const float* mu     = (const float*)d_in[1];
  const float* logvar = (const float*)d_in[2];
  const float* alpha  = (const float*)d_in[3];
  const float* wq = (const float*)d_in[6];
  const float* wk = (const float*)d_in[7];
  const float* wv = (const float*)d_in[8];
  const float* wp = (const float*)d_in[9];
  const float* bp = (const float*)d_in[10];

  float* out      = (float*)d_out;
  float* attn_out = out + (size_t)M_ * C_;

  char* ws = (char*)d_ws;
  ushort_t* xb     = (ushort_t*)(ws);
  ushort_t* kp     = (ushort_t*)(ws + (size_t)8  * 1048576);
  ushort_t* vp     = (ushort_t*)(ws + (size_t)16 * 1048576);
  ushort_t* Qhs    = (ushort_t*)(ws + (size_t)24 * 1048576);
  ushort_t* Khs    = (ushort_t*)(ws + (size_t)32 * 1048576);
  ushort_t* Vts    = (ushort_t*)(ws + (size_t)40 * 1048576);
  ushort_t* wb     = (ushort_t*)(ws + (size_t)48 * 1048576);
  float*    biasv  = (float*)   (ws + (size_t)56 * 1048576);
  float*    l2part = (float*)   (ws + (size_t)57 * 1048576);
  ushort_t* Og     = xb;

  prep_pack_kernel<<<2048, 256, 0, stream>>>(x, mu, logvar, wq, wk, wv, wp,
                                             xb, kp, vp, wb, l2part);
  bias_reduce_kernel<<<16, 256, 0, stream>>>(alpha, l2part, biasv);
  gemm_qkv_kernel<<<dim3(32, 8, 3), 256, 0, stream>>>(xb, kp, vp, wb, Qhs, Khs, Vts);
  attn_kernel<<<dim3(128, 8), 256, 0, stream>>>(Qhs, Khs, Vts, biasv, attn_out, Og);
  gemm_out_kernel<<<dim3(32, 8), 256, 0, stream>>>(Og, wb, bp, out);
}

// Round 12
// 110.005 us; speedup vs baseline: 1.2540x; 1.0110x over previous
//
#include <hip/hip_runtime.h>
#include <hip/hip_bf16.h>

// Problem constants
#define B_  8
#define N_  512
#define C_  1024
#define H_  16
#define HD_ 64
#define M_  4096   // B*N

typedef float  f32x4  __attribute__((ext_vector_type(4)));
typedef __bf16 bf16x8 __attribute__((ext_vector_type(8)));
typedef unsigned short ushort_t;

__device__ __forceinline__ ushort_t f2bf(float f) {
  union { float f; unsigned int u; } un; un.f = f;
  unsigned int u = un.u;
  return (ushort_t)((u + 0x7fffu + ((u >> 16) & 1u)) >> 16);  // RNE
}

// async global->LDS, 16B per lane; lds pointer must be wave-uniform (lane*16 added by HW)
__device__ __forceinline__ void gload16(const void* g, void* l) {
  __builtin_amdgcn_global_load_lds((const __attribute__((address_space(1))) void*)g,
                                   (__attribute__((address_space(3))) void*)l, 16, 0, 0);
}
#define SBAR()  __builtin_amdgcn_s_barrier()
#define SCHED() __builtin_amdgcn_sched_barrier(0)
#define VMCNT4() asm volatile("s_waitcnt vmcnt(4)" ::: "memory")
#define VMCNT0() asm volatile("s_waitcnt vmcnt(0)" ::: "memory")

// Packed GEMM-operand layout (verified R8/R9):
//   PACK(row,k) = (((row>>7)*32 + (k>>5))*4 + ((k>>3)&3))*1024 + (row&127)*8 + (k&7)
// [mtile][kt][chunk4][row128][8] — the exact linear order gemm staging consumes.

// ---------------------------------------------------------------------------
// Kernel 1: tile-packed prep. Block = one [128r x 32k] tile. (verified R9)
// ---------------------------------------------------------------------------
__global__ __launch_bounds__(256) void prep_pack_kernel(
    const float* __restrict__ x, const float* __restrict__ mu,
    const float* __restrict__ logvar,
    const float* __restrict__ wq, const float* __restrict__ wk,
    const float* __restrict__ wv, const float* __restrict__ wp,
    ushort_t* __restrict__ xb, ushort_t* __restrict__ kp, ushort_t* __restrict__ vp,
    ushort_t* __restrict__ wb, float* __restrict__ l2part) {
  const int bid = blockIdx.x, t = threadIdx.x;
  const int row = t >> 1, cg = (t & 1) * 16;   // row 0..127, k-group 0 or 16
  const int c0 = cg >> 3;                      // chunk base: 0 or 2

  if (bid < 1024) {
    const int mt = bid >> 5, kt = bid & 31;
    const size_t src = (size_t)(mt * 128 + row) * 1024 + kt * 32 + cg;
    ushort_t tx[16] __attribute__((aligned(16)));
    ushort_t tk[16] __attribute__((aligned(16)));
    ushort_t tv[16] __attribute__((aligned(16)));
    float l2 = 0.f;
#pragma unroll
    for (int j = 0; j < 4; ++j) {
      float4 xv = *(const float4*)(x + src + j * 4);
      float4 mv = *(const float4*)(mu + src + j * 4);
      float4 lv = *(const float4*)(logvar + src + j * 4);
      float xa[4] = {xv.x, xv.y, xv.z, xv.w};
      float ma[4] = {mv.x, mv.y, mv.z, mv.w};
      float la[4] = {lv.x, lv.y, lv.z, lv.w};
#pragma unroll
      for (int i = 0; i < 4; ++i) {
        int e = j * 4 + i;
        float bv  = __expf(la[i]) + 8.0f;   // exp(logvar) + sqrt(HD)
        float inv = 1.0f / bv;
        float kf  = ma[i] * inv;
        l2 += ma[i] * kf;                   // mu^2 / bv
        tx[e] = f2bf(xa[i]); tk[e] = f2bf(kf); tv[e] = f2bf(8.0f * kf);
      }
    }
    const size_t tb = (size_t)((mt * 32 + kt) * 4) * 1024 + row * 8;
    *(bf16x8*)(xb + tb + c0 * 1024)       = *(const bf16x8*)(tx);
    *(bf16x8*)(xb + tb + (c0 + 1) * 1024) = *(const bf16x8*)(tx + 8);
    *(bf16x8*)(kp + tb + c0 * 1024)       = *(const bf16x8*)(tk);
    *(bf16x8*)(kp + tb + (c0 + 1) * 1024) = *(const bf16x8*)(tk + 8);
    *(bf16x8*)(vp + tb + c0 * 1024)       = *(const bf16x8*)(tv);
    *(bf16x8*)(vp + tb + (c0 + 1) * 1024) = *(const bf16x8*)(tv + 8);
    l2 += __shfl_xor(l2, 1);               // pair holds full 32-k partial
    if ((t & 1) == 0) l2part[(size_t)(mt * 128 + row) * 32 + kt] = l2;
  } else {
    const int idx = bid - 1024;
    const int sel = idx >> 8, nt = (idx >> 5) & 7, kt = idx & 31;
    const float* src = sel == 0 ? wq : sel == 1 ? wk : sel == 2 ? wv : wp;
    const size_t so = (size_t)(nt * 128 + row) * 1024 + kt * 32 + cg;
    ushort_t tw[16] __attribute__((aligned(16)));
#pragma unroll
    for (int j = 0; j < 4; ++j) {
      float4 v = *(const float4*)(src + so + j * 4);
      tw[j * 4 + 0] = f2bf(v.x); tw[j * 4 + 1] = f2bf(v.y);
      tw[j * 4 + 2] = f2bf(v.z); tw[j * 4 + 3] = f2bf(v.w);
    }
    ushort_t* dst = wb + (size_t)sel * 1048576;
    const size_t tb = (size_t)((nt * 32 + kt) * 4) * 1024 + row * 8;
    *(bf16x8*)(dst + tb + c0 * 1024)       = *(const bf16x8*)(tw);
    *(bf16x8*)(dst + tb + (c0 + 1) * 1024) = *(const bf16x8*)(tw + 8);
  }
}

// ---------------------------------------------------------------------------
// GEMM core, 128x128 tile, BK=32, 256 thr, RING-3 LDS (48KB, 3 blocks/CU).
// PACKED operands: staging is 2 fully-contiguous 8KB runs per tile.
// ---------------------------------------------------------------------------
__device__ __forceinline__ void gemm_tile_r3(const ushort_t* __restrict__ Ag,
                                             const ushort_t* __restrict__ Wg,
                                             int amt, int ant, f32x4 acc[4][4],
                                             ushort_t* lds) {
  const int t = threadIdx.x;
  const int w = t >> 6, lane = t & 63;
  const int wm = w >> 1, wn = w & 1;
  const int chunk = lane >> 4, r15 = lane & 15;
  const int s0 = t, s1 = t + 256;

#define RSTAGE(kt, buf)                                                           \
  do {                                                                            \
    const ushort_t* sa = Ag + (size_t)(amt * 32 + (kt)) * 4096;                   \
    const ushort_t* sb = Wg + (size_t)(ant * 32 + (kt)) * 4096;                   \
    gload16(sa + s0 * 8, lds + (buf) * 4096 + (s0 & ~63) * 8);                    \
    gload16(sa + s1 * 8, lds + (buf) * 4096 + (s1 & ~63) * 8);                    \
    gload16(sb + s0 * 8, lds + 12288 + (buf) * 4096 + (s0 & ~63) * 8);            \
    gload16(sb + s1 * 8, lds + 12288 + (buf) * 4096 + (s1 & ~63) * 8);            \
  } while (0)

#define RCOMPUTE(j)                                                               \
  do {                                                                            \
    const ushort_t* Ab = lds + (j) * 4096;                                        \
    const ushort_t* Bb = lds + 12288 + (j) * 4096;                                \
    bf16x8 af[4], bw[4];                                                          \
    _Pragma("unroll")                                                             \
    for (int mi = 0; mi < 4; ++mi)                                                \
      af[mi] = *(const bf16x8*)(Ab + (chunk * 128 + wm * 64 + mi * 16 + r15) * 8);\
    _Pragma("unroll")                                                             \
    for (int ni = 0; ni < 4; ++ni)                                                \
      bw[ni] = *(const bf16x8*)(Bb + (chunk * 128 + wn * 64 + ni * 16 + r15) * 8);\
    __builtin_amdgcn_s_setprio(1);                                                \
    _Pragma("unroll")                                                             \
    for (int mi = 0; mi < 4; ++mi)                                                \
      _Pragma("unroll")                                                           \
      for (int ni = 0; ni < 4; ++ni)                                              \
        acc[mi][ni] = __builtin_amdgcn_mfma_f32_16x16x32_bf16(af[mi], bw[ni],     \
                                                              acc[mi][ni], 0, 0, 0); \
    __builtin_amdgcn_s_setprio(0);                                                \
    SCHED();                                                                      \
  } while (0)

  RSTAGE(0, 0); RSTAGE(1, 1);
  VMCNT4();
  SBAR(); SCHED();
  for (int kt0 = 0; kt0 < 30; kt0 += 3) {
    RSTAGE(kt0 + 2, 2); RCOMPUTE(0); VMCNT4(); SBAR(); SCHED();
    RSTAGE(kt0 + 3, 0); RCOMPUTE(1); VMCNT4(); SBAR(); SCHED();
    RSTAGE(kt0 + 4, 1); RCOMPUTE(2); VMCNT4(); SBAR(); SCHED();
  }
  RCOMPUTE(0); VMCNT0(); SBAR(); SCHED();
  RCOMPUTE(1);
#undef RSTAGE
#undef RCOMPUTE
}

// ---------------------------------------------------------------------------
// Kernel 2: Q/K/V projections + (z==0,y==0 blocks) fused bias reduce.
// PACKED outputs: Qhs[bh][qt][chunk8][row64][8], Khs[bh][kt][chunk8][row128][8],
// Vts[bh][kt][chunk16][d64][8].   (verified R10: Output 0 passed)
// ---------------------------------------------------------------------------
__global__ __launch_bounds__(256, 3) void gemm_qkv_kernel(
    const ushort_t* __restrict__ xb, const ushort_t* __restrict__ kp,
    const ushort_t* __restrict__ vp, const ushort_t* __restrict__ wb,
    const float* __restrict__ alpha, const float* __restrict__ l2part,
    float* __restrict__ biasv,
    ushort_t* __restrict__ Qhs, ushort_t* __restrict__ Khs, ushort_t* __restrict__ Vts) {
  __shared__ ushort_t lds[24576];
  const int z = blockIdx.z;
  const ushort_t* Ag = z == 0 ? xb : z == 1 ? kp : vp;
  const ushort_t* Wg = wb + (size_t)z * 1048576;
  const int m0 = blockIdx.x * 128, n0 = blockIdx.y * 128;
  const int t = threadIdx.x;

  // fused bias reduce: 32 blocks (z=0,y=0) cover all 4096 rows before staging.
  if (z == 0 && blockIdx.y == 0 && t < 128) {
    int row = m0 + t;
    const float* p = l2part + (size_t)row * 32;
    float s = 0.f;
#pragma unroll
    for (int j = 0; j < 8; ++j) {
      float4 v = *(const float4*)(p + j * 4);
      s += (v.x + v.y) + (v.z + v.w);
    }
    biasv[row] = __logf(alpha[row]) - 0.5f * s;
  }

  f32x4 acc[4][4] = {};
  gemm_tile_r3(Ag, Wg, blockIdx.x, blockIdx.y, acc, lds);
  const int w = t >> 6, lane = t & 63;
  const int wm = w >> 1, wn = w & 1;
  const int hi = lane >> 4, r15 = lane & 15;
  const int b = m0 >> 9, h0 = n0 >> 6;

  __syncthreads();
  if (z < 2) {
    ushort_t* T = lds;                       // [128][136]
#pragma unroll
    for (int mi = 0; mi < 4; ++mi)
#pragma unroll
      for (int ni = 0; ni < 4; ++ni)
#pragma unroll
        for (int q = 0; q < 4; ++q) {
          int row = wm * 64 + mi * 16 + hi * 4 + q;
          int col = wn * 64 + ni * 16 + r15;
          T[row * 136 + col] = f2bf(acc[mi][ni][q]);
        }
    __syncthreads();
    if (z == 0) {
      const int qt0 = (m0 & 511) >> 6;
#pragma unroll
      for (int i = 0; i < 8; ++i) {
        int c = t + 256 * i;
        int row64 = c & 63, qt_l = (c >> 6) & 1, chunk = (c >> 7) & 7, head_l = (c >> 10) & 1;
        bf16x8 v = *(const bf16x8*)(T + (qt_l * 64 + row64) * 136 + head_l * 64 + chunk * 8);
        int bh = b * 16 + h0 + head_l;
        *(bf16x8*)(Qhs + ((size_t)((bh * 8 + qt0 + qt_l) * 8 + chunk) * 64 + row64) * 8) = v;
      }
    } else {
      const int kt = (m0 & 511) >> 7;
#pragma unroll
      for (int i = 0; i < 8; ++i) {
        int c = t + 256 * i;
        int row128 = c & 127, chunk = (c >> 7) & 7, head_l = (c >> 10) & 1;
        bf16x8 v = *(const bf16x8*)(T + row128 * 136 + head_l * 64 + chunk * 8);
        int bh = b * 16 + h0 + head_l;
        *(bf16x8*)(Khs + ((size_t)((bh * 4 + kt) * 8 + chunk) * 128 + row128) * 8) = v;
      }
    }
  } else {
    ushort_t* T = lds;                       // [128][129]
#pragma unroll
    for (int mi = 0; mi < 4; ++mi)
#pragma unroll
      for (int ni = 0; ni < 4; ++ni)
#pragma unroll
        for (int q = 0; q < 4; ++q) {
          int row = wm * 64 + mi * 16 + hi * 4 + q;
          int col = wn * 64 + ni * 16 + r15;
          T[row * 129 + col] = f2bf(acc[mi][ni][q]);
        }
    __syncthreads();
    const int kt = (m0 & 511) >> 7;
#pragma unroll
    for (int i = 0; i < 8; ++i) {
      int c = t + 256 * i;
      int d64 = c & 63, head_l = (c >> 6) & 1, chunkp = (c >> 7) & 15;
      bf16x8 v;
#pragma unroll
      for (int j = 0; j < 8; ++j)
        v[j] = *(const __bf16*)(T + (chunkp * 8 + j) * 129 + head_l * 64 + d64);
      int bh = b * 16 + h0 + head_l;
      *(bf16x8*)(Vts + ((size_t)((bh * 4 + kt) * 16 + chunkp) * 64 + d64) * 8) = v;
    }
  }
}

// ---------------------------------------------------------------------------
// Kernel 3: attention. attn_out on the R9-verified direct store path
// (R10's per-wave LDS bounce produced wrong attn values — reverted).
// ---------------------------------------------------------------------------
__global__ __launch_bounds__(256, 2) void attn_kernel(
    const ushort_t* __restrict__ Qhs, const ushort_t* __restrict__ Khs,
    const ushort_t* __restrict__ Vts, const float* __restrict__ biasv,
    float* __restrict__ attn_out, ushort_t* __restrict__ Og) {
  __shared__ ushort_t Qt[4096];
  __shared__ ushort_t KV[16384];
  __shared__ ushort_t Pl[8192];
  __shared__ float biasl[512];
  const int bh = blockIdx.x, qt = blockIdx.y;
  const int b = bh >> 4, h = bh & 15;
  const int t = threadIdx.x, w = t >> 6, lane = t & 63;
  const int hi = lane >> 4, r15 = lane & 15;

  {
    float2 bv2 = *(const float2*)(biasv + b * 512 + t * 2);
    biasl[t * 2] = bv2.x; biasl[t * 2 + 1] = bv2.y;
  }
  {
    const ushort_t* sq = Qhs + (size_t)(bh * 8 + qt) * 4096;
    gload16(sq + t * 8, Qt + (t & ~63) * 8);
    gload16(sq + (t + 256) * 8, Qt + ((t + 256) & ~63) * 8);
  }

#define STAGE_K(kt, buf)                                                               \
  do {                                                                                 \
    const ushort_t* sk = Khs + (size_t)(bh * 4 + (kt)) * 8192;                         \
    _Pragma("unroll")                                                                  \
    for (int r = 0; r < 4; ++r) {                                                      \
      int s = r * 256 + t;                                                             \
      gload16(sk + s * 8, KV + (buf) * 8192 + (s & ~63) * 8);                          \
    }                                                                                  \
  } while (0)
#define STAGE_V(kt, buf)                                                               \
  do {                                                                                 \
    const ushort_t* sv = Vts + (size_t)(bh * 4 + (kt)) * 8192;                         \
    _Pragma("unroll")                                                                  \
    for (int r = 0; r < 4; ++r) {                                                      \
      int s = r * 256 + t;                                                             \
      gload16(sv + s * 8, KV + (buf) * 8192 + (s & ~63) * 8);                          \
    }                                                                                  \
  } while (0)

  STAGE_K(0, 0);
  f32x4 acc[32] = {};
  bf16x8 aq[2];
  int cur = 0;

#pragma unroll
  for (int kt = 0; kt < 4; ++kt) {
    if (kt < 3) STAGE_K(kt + 1, cur ^ 1);
    else        STAGE_V(0, cur ^ 1);
    VMCNT4();
    SBAR();
    SCHED();
    if (kt == 0) {
#pragma unroll
      for (int ks = 0; ks < 2; ++ks)
        aq[ks] = *(const bf16x8*)(Qt + ((ks * 4 + hi) * 64 + w * 16 + r15) * 8);
    }
    __builtin_amdgcn_s_setprio(1);
#pragma unroll
    for (int mf = 0; mf < 8; ++mf)
#pragma unroll
      for (int ks = 0; ks < 2; ++ks) {
        bf16x8 bk = *(const bf16x8*)(KV + cur * 8192 + ((ks * 4 + hi) * 128 + mf * 16 + r15) * 8);
        acc[kt * 8 + mf] = __builtin_amdgcn_mfma_f32_16x16x32_bf16(aq[ks], bk, acc[kt * 8 + mf], 0, 0, 0);
      }
    __builtin_amdgcn_s_setprio(0);
    SCHED();
    SBAR();
    SCHED();
    cur ^= 1;
  }

  float mx[4] = {-1e30f, -1e30f, -1e30f, -1e30f};
#pragma unroll
  for (int f = 0; f < 32; ++f) {
    float bv = biasl[f * 16 + r15];
#pragma unroll
    for (int q = 0; q < 4; ++q) {
      acc[f][q] += bv;
      mx[q] = fmaxf(mx[q], acc[f][q]);
    }
  }
#pragma unroll
  for (int q = 0; q < 4; ++q) {
    mx[q] = fmaxf(mx[q], __shfl_xor(mx[q], 1));
    mx[q] = fmaxf(mx[q], __shfl_xor(mx[q], 2));
    mx[q] = fmaxf(mx[q], __shfl_xor(mx[q], 4));
    mx[q] = fmaxf(mx[q], __shfl_xor(mx[q], 8));
  }
  float sm[4] = {0.f, 0.f, 0.f, 0.f};
#pragma unroll
  for (int f = 0; f < 32; ++f)
#pragma unroll
    for (int q = 0; q < 4; ++q) {
      float p = __expf(acc[f][q] - mx[q]);
      acc[f][q] = p;
      sm[q] += p;
    }
#pragma unroll
  for (int q = 0; q < 4; ++q) {
    sm[q] += __shfl_xor(sm[q], 1);
    sm[q] += __shfl_xor(sm[q], 2);
    sm[q] += __shfl_xor(sm[q], 4);
    sm[q] += __shfl_xor(sm[q], 8);
    sm[q] = 1.0f / sm[q];
  }
#pragma unroll
  for (int f = 0; f < 32; ++f)
#pragma unroll
    for (int q = 0; q < 4; ++q)
      acc[f][q] *= sm[q];

  f32x4 oacc[4] = {};
#pragma unroll
  for (int kt = 0; kt < 4; ++kt) {
    if (kt < 3) STAGE_V(kt + 1, cur ^ 1);
#pragma unroll
    for (int fl = 0; fl < 8; ++fl) {
      int f = kt * 8 + fl;
      int chunkp = fl * 2 + (r15 >> 3);
#pragma unroll
      for (int q = 0; q < 4; ++q)
        Pl[w * 2048 + (chunkp * 16 + hi * 4 + q) * 8 + (lane & 7)] = f2bf(acc[f][q]);
    }
    if (kt < 3) VMCNT4(); else VMCNT0();
    SBAR();
    SCHED();
    __builtin_amdgcn_s_setprio(1);
#pragma unroll
    for (int ks = 0; ks < 4; ++ks) {
      bf16x8 pa = *(const bf16x8*)(Pl + w * 2048 + ((ks * 4 + hi) * 16 + r15) * 8);
#pragma unroll
      for (int df = 0; df < 4; ++df) {
        bf16x8 vb = *(const bf16x8*)(KV + cur * 8192 + ((ks * 4 + hi) * 64 + df * 16 + r15) * 8);
        oacc[df] = __builtin_amdgcn_mfma_f32_16x16x32_bf16(pa, vb, oacc[df], 0, 0, 0);
      }
    }
    __builtin_amdgcn_s_setprio(0);
    SCHED();
    SBAR();
    SCHED();
    cur ^= 1;
  }

  // ---- deferred stores: attn (fp32, R9-verified direct path) ----
  float* ao = attn_out + ((size_t)bh * 512 + qt * 64 + w * 16 + hi * 4) * 512 + r15;
#pragma unroll
  for (int f = 0; f < 32; ++f)
#pragma unroll
    for (int q = 0; q < 4; ++q)
      ao[(size_t)q * 512 + f * 16] = acc[f][q];

  // ---- Og (bf16, PACKED for gemm_out) ----
  {
    const int mtile = b * 4 + (qt >> 1);
    const int rowl = (qt & 1) * 64 + w * 16 + hi * 4;
#pragma unroll
    for (int df = 0; df < 4; ++df) {
      int kto = h * 2 + (df >> 1);
      int chunko = (df & 1) * 2 + (r15 >> 3);
      size_t ob = ((size_t)((mtile * 32 + kto) * 4 + chunko) * 1024 + (r15 & 7));
#pragma unroll
      for (int q = 0; q < 4; ++q)
        Og[ob + (size_t)(rowl + q) * 8] = f2bf(oacc[df][q]);
    }
  }
#undef STAGE_K
#undef STAGE_V
}

// ---------------------------------------------------------------------------
// Kernel 4: out = O @ wp^T + b_p. LDS epilogue (two 32KB halves) -> float4
// stores with bias added on the read pass. (verified R10: Output 0 passed)
// ---------------------------------------------------------------------------
__global__ __launch_bounds__(256, 3) void gemm_out_kernel(
    const ushort_t* __restrict__ Og, const ushort_t* __restrict__ wb,
    const float* __restrict__ bp, float* __restrict__ out) {
  __shared__ ushort_t lds[24576];
  const int m0 = blockIdx.x * 128, n0 = blockIdx.y * 128;
  f32x4 acc[4][4] = {};
  gemm_tile_r3(Og, wb + 3 * 1048576, blockIdx.x, blockIdx.y, acc, lds);
  const int t = threadIdx.x, w = t >> 6, lane = t & 63;
  const int wm = w >> 1, wn = w & 1;
  const int hi = lane >> 4, r15 = lane & 15;
  float* T2 = (float*)lds;                   // [64][128] fp32 = 32KB per half
#pragma unroll
  for (int hh = 0; hh < 2; ++hh) {
    __syncthreads();                         // prior phase's LDS reads done
    if (wm == hh) {
#pragma unroll
      for (int mi = 0; mi < 4; ++mi)
#pragma unroll
        for (int ni = 0; ni < 4; ++ni)
#pragma unroll
          for (int q = 0; q < 4; ++q) {
            int row = mi * 16 + hi * 4 + q;  // 0..63 within half
            int col = wn * 64 + ni * 16 + r15;
            T2[row * 128 + col] = acc[mi][ni][q];
          }
    }
    __syncthreads();
#pragma unroll
    for (int i = 0; i < 8; ++i) {
      int c = t + 256 * i;
      int row = c >> 5, col0 = (c & 31) * 4;
      float4 v = *(const float4*)(T2 + row * 128 + col0);
      float4 bb = *(const float4*)(bp + n0 + col0);
      v.x += bb.x; v.y += bb.y; v.z += bb.z; v.w += bb.w;
      *(float4*)(out + (size_t)(m0 + hh * 64 + row) * 1024 + n0 + col0) = v;
    }
  }
}

// ---------------------------------------------------------------------------
// Launch. Workspace:
//   0 xb | 8MB kp | 16MB vp | 24MB Qhs | 32MB Khs | 40MB Vts | 48MB wb
//   56MB biasv (16KB) | 57MB l2part (512KB).  Og reuses xb.
// ---------------------------------------------------------------------------
extern "C" void kernel_launch(void* const* d_in, const int* in_sizes, int n_in,
                              void* d_out, int out_size, void* d_ws, size_t ws_size,
                              hipStream_t stream) {
  const float* x      = (const float*)d_in[0];
  const float* mu     = (const float*)d_in[1];
  const float* logvar = (const float*)d_in[2];
  const float* alpha  = (const float*)d_in[3];
  const float* wq = (const float*)d_in[6];
  const float* wk = (const float*)d_in[7];
  const float* wv = (const float*)d_in[8];
  const float* wp = (const float*)d_in[9];
  const float* bp = (const float*)d_in[10];

  float* out      = (float*)d_out;
  float* attn_out = out + (size_t)M_ * C_;

  char* ws = (char*)d_ws;
  ushort_t* xb     = (ushort_t*)(ws);
  ushort_t* kp     = (ushort_t*)(ws + (size_t)8  * 1048576);
  ushort_t* vp     = (ushort_t*)(ws + (size_t)16 * 1048576);
  ushort_t* Qhs    = (ushort_t*)(ws + (size_t)24 * 1048576);
  ushort_t* Khs    = (ushort_t*)(ws + (size_t)32 * 1048576);
  ushort_t* Vts    = (ushort_t*)(ws + (size_t)40 * 1048576);
  ushort_t* wb     = (ushort_t*)(ws + (size_t)48 * 1048576);
  float*    biasv  = (float*)   (ws + (size_t)56 * 1048576);
  float*    l2part = (float*)   (ws + (size_t)57 * 1048576);
  ushort_t* Og     = xb;

  prep_pack_kernel<<<2048, 256, 0, stream>>>(x, mu, logvar, wq, wk, wv, wp,
                                             xb, kp, vp, wb, l2part);
  gemm_qkv_kernel<<<dim3(32, 8, 3), 256, 0, stream>>>(xb, kp, vp, wb,
                                                      alpha, l2part, biasv,
                                                      Qhs, Khs, Vts);
  attn_kernel<<<dim3(128, 8), 256, 0, stream>>>(Qhs, Khs, Vts, biasv, attn_out, Og);
  gemm_out_kernel<<<dim3(32, 8), 256, 0, stream>>>(Og, wb, bp, out);
}